// Round 1
// baseline (4419.065 us; speedup 1.0000x reference)
//
#include <hip/hip_runtime.h>
#include <math.h>

#define NGRAPH 1000
#define SCAN_BLOCK 1024

// ---------------- CSR build ----------------

__global__ __launch_bounds__(256) void hist_kernel(const int* __restrict__ dst, int E,
                                                   int* __restrict__ counts) {
  for (int e = blockIdx.x * blockDim.x + threadIdx.x; e < E; e += gridDim.x * blockDim.x)
    atomicAdd(&counts[dst[e]], 1);
}

__global__ __launch_bounds__(SCAN_BLOCK) void scan_block_sums(const int* __restrict__ counts, int n,
                                                              int* __restrict__ blockSums) {
  __shared__ int s[SCAN_BLOCK];
  int i = blockIdx.x * SCAN_BLOCK + threadIdx.x;
  s[threadIdx.x] = (i < n) ? counts[i] : 0;
  __syncthreads();
  for (int off = SCAN_BLOCK / 2; off > 0; off >>= 1) {
    if (threadIdx.x < off) s[threadIdx.x] += s[threadIdx.x + off];
    __syncthreads();
  }
  if (threadIdx.x == 0) blockSums[blockIdx.x] = s[0];
}

__global__ __launch_bounds__(SCAN_BLOCK) void scan_offsets(const int* __restrict__ blockSums, int nb,
                                                           int* __restrict__ blockOffs) {
  __shared__ int s[SCAN_BLOCK];
  int v = (threadIdx.x < nb) ? blockSums[threadIdx.x] : 0;
  s[threadIdx.x] = v;
  __syncthreads();
  for (int off = 1; off < SCAN_BLOCK; off <<= 1) {
    int t = (threadIdx.x >= off) ? s[threadIdx.x - off] : 0;
    __syncthreads();
    s[threadIdx.x] += t;
    __syncthreads();
  }
  if (threadIdx.x < nb) blockOffs[threadIdx.x] = s[threadIdx.x] - v;  // exclusive
}

__global__ __launch_bounds__(SCAN_BLOCK) void scan_apply(const int* __restrict__ counts, int n,
                                                         const int* __restrict__ blockOffs,
                                                         int* __restrict__ row_ptr, int total) {
  __shared__ int s[SCAN_BLOCK];
  int i = blockIdx.x * SCAN_BLOCK + threadIdx.x;
  int v = (i < n) ? counts[i] : 0;
  s[threadIdx.x] = v;
  __syncthreads();
  for (int off = 1; off < SCAN_BLOCK; off <<= 1) {
    int t = (threadIdx.x >= off) ? s[threadIdx.x - off] : 0;
    __syncthreads();
    s[threadIdx.x] += t;
    __syncthreads();
  }
  if (i < n) row_ptr[i] = blockOffs[blockIdx.x] + s[threadIdx.x] - v;
  if (i == 0) row_ptr[n] = total;
}

__global__ __launch_bounds__(256) void fill_kernel(const int* __restrict__ src,
                                                   const int* __restrict__ dst, int E,
                                                   const int* __restrict__ row_ptr,
                                                   int* __restrict__ row_fill,
                                                   int* __restrict__ col) {
  for (int e = blockIdx.x * blockDim.x + threadIdx.x; e < E; e += gridDim.x * blockDim.x) {
    int d = dst[e];
    int pos = atomicAdd(&row_fill[d], 1);
    col[row_ptr[d] + pos] = src[e];
  }
}

// ---------------- Fused GIN layer: agg + Lin-ReLU-Lin + BN-stat partials ----------------
// lanes-per-node = FIN; block = FIN*NPB threads.

template <int FIN, int FMID, int FOUT, int NPB>
__global__ __launch_bounds__(FIN * NPB) void gin_kernel(
    const float* __restrict__ x, const int* __restrict__ row_ptr, const int* __restrict__ col,
    const float* __restrict__ epsp, const float* __restrict__ W1, const float* __restrict__ b1,
    const float* __restrict__ W2, const float* __restrict__ b2, float* __restrict__ out,
    float* __restrict__ stats, int n) {
  __shared__ float W1s[FIN * FMID];
  __shared__ float W2s[FMID * FOUT];
  __shared__ float b1s[FMID];
  __shared__ float b2s[FOUT];
  __shared__ float hbuf[NPB][FIN];
  __shared__ float mbuf[NPB][FMID];
  const int tid = threadIdx.x;
  for (int i = tid; i < FIN * FMID; i += blockDim.x) W1s[i] = W1[i];
  for (int i = tid; i < FMID * FOUT; i += blockDim.x) W2s[i] = W2[i];
  if (tid < FMID) b1s[tid] = b1[tid];
  if (tid < FOUT) b2s[tid] = b2[tid];
  const float eps1 = 1.0f + epsp[0];
  __syncthreads();

  const int ln = tid / FIN;
  const int f = tid % FIN;
  float ssum = 0.f, ssq = 0.f;

  for (int base = blockIdx.x * NPB; base < n; base += gridDim.x * NPB) {
    int node = base + ln;
    bool valid = node < n;
    float a = 0.f;
    if (valid) {
      a = eps1 * x[(size_t)node * FIN + f];
      int rs = row_ptr[node], re = row_ptr[node + 1];
      for (int e = rs; e < re; e++) {
        int c = col[e];
        a += x[(size_t)c * FIN + f];
      }
    }
    hbuf[ln][f] = a;
    __syncthreads();
    if (f < FMID) {
      float m = b1s[f];
#pragma unroll 8
      for (int k = 0; k < FIN; k++) m += hbuf[ln][k] * W1s[k * FMID + f];
      mbuf[ln][f] = fmaxf(m, 0.f);
    }
    __syncthreads();
    if (f < FOUT) {
      float o = b2s[f];
#pragma unroll 8
      for (int k = 0; k < FMID; k++) o += mbuf[ln][k] * W2s[k * FOUT + f];
      if (valid) {
        out[(size_t)node * FOUT + f] = o;
        ssum += o;
        ssq += o * o;
      }
    }
    __syncthreads();
  }

  // block-level stat reduction: sums then sumsq -> 2 atomics per feature per block
  if (f < FOUT) hbuf[ln][f] = ssum;
  __syncthreads();
  if (tid < FOUT) {
    float t = 0.f;
    for (int l = 0; l < NPB; l++) t += hbuf[l][tid];
    atomicAdd(&stats[tid], t);
  }
  __syncthreads();
  if (f < FOUT) hbuf[ln][f] = ssq;
  __syncthreads();
  if (tid < FOUT) {
    float t = 0.f;
    for (int l = 0; l < NPB; l++) t += hbuf[l][tid];
    atomicAdd(&stats[128 + tid], t);
  }
}

// ---------------- BatchNorm apply (in place) ----------------

__global__ __launch_bounds__(256) void bn_kernel(float* __restrict__ x,
                                                 const float* __restrict__ stats,
                                                 const float* __restrict__ gamma,
                                                 const float* __restrict__ beta, int total,
                                                 int fmask, float invN) {
  for (int idx = blockIdx.x * blockDim.x + threadIdx.x; idx < total;
       idx += gridDim.x * blockDim.x) {
    int g = idx & fmask;
    float mu = stats[g] * invN;
    float var = stats[128 + g] * invN - mu * mu;
    float sc = gamma[g] * rsqrtf(var + 1e-5f);
    x[idx] = (x[idx] - mu) * sc + beta[g];
  }
}

// ---------------- Readout ----------------

__global__ __launch_bounds__(256) void readout_sums(const float* __restrict__ x3,
                                                    const int* __restrict__ batch,
                                                    float* __restrict__ cnt,
                                                    float* __restrict__ summ, int n) {
  int total = n * 16;
  for (int idx = blockIdx.x * blockDim.x + threadIdx.x; idx < total;
       idx += gridDim.x * blockDim.x) {
    int node = idx >> 4;
    int f = idx & 15;
    int g = batch[node];
    atomicAdd(&summ[g * 16 + f], x3[idx]);
    if (f == 0) atomicAdd(&cnt[g], 1.0f);
  }
}

__global__ __launch_bounds__(256) void readout_c(const float* __restrict__ cnt,
                                                 const float* __restrict__ summ,
                                                 const float* __restrict__ attW,
                                                 const float* __restrict__ attb,
                                                 float* __restrict__ cvals, int ng) {
  int idx = blockIdx.x * blockDim.x + threadIdx.x;
  if (idx >= ng * 16) return;
  int g = idx >> 4;
  int fo = idx & 15;
  float inv = 1.0f / fmaxf(cnt[g], 1.0f);
  float acc = attb[fo];
  for (int k = 0; k < 16; k++) acc += (summ[g * 16 + k] * inv) * attW[k * 16 + fo];
  cvals[idx] = 1.0f / (1.0f + expf(-acc));
}

__global__ __launch_bounds__(256) void readout_pool(const float* __restrict__ x3,
                                                    const int* __restrict__ batch,
                                                    const float* __restrict__ cvals,
                                                    float* __restrict__ hg, int n) {
  int total = n * 16;
  for (int idx = blockIdx.x * blockDim.x + threadIdx.x; idx < total;
       idx += gridDim.x * blockDim.x) {
    int node = idx >> 4;
    int f = idx & 15;
    int g = batch[node];
    float xv = x3[idx];
    float p = xv * cvals[g * 16 + f];
    // dot across the node's 16 lanes (16-lane groups are wave-aligned; n*16 % 256 == 0)
    for (int m = 8; m >= 1; m >>= 1) p += __shfl_xor(p, m, 16);
    float gate = 1.0f / (1.0f + expf(-p));
    atomicAdd(&hg[g * 16 + f], gate * xv);
  }
}

// ---------------- EFN + final ----------------

__device__ inline void efn_dev(const float* hi, const float* hj, const float* aW1,
                               const float* ab1, const float* aW2, const float* ab2,
                               const float* mW, const float* mb, float* o16) {
  float h[32];
#pragma unroll
  for (int k = 0; k < 16; k++) {
    h[k] = hi[k];
    h[16 + k] = hj[k];
  }
  float m8[8];
#pragma unroll
  for (int o = 0; o < 8; o++) {
    float t = ab1[o];
#pragma unroll
    for (int k = 0; k < 32; k++) t += h[k] * aW1[k * 8 + o];
    m8[o] = fmaxf(t, 0.f);
  }
  float enc[32];
#pragma unroll
  for (int o = 0; o < 32; o++) {
    float t = ab2[o];
#pragma unroll
    for (int k = 0; k < 8; k++) t += m8[k] * aW2[k * 32 + o];
    float att = tanhf(t);
    enc[o] = att * h[o] + h[o];
  }
#pragma unroll
  for (int o = 0; o < 16; o++) {
    float t = mb[o];
#pragma unroll
    for (int k = 0; k < 32; k++) t += enc[k] * mW[k * 16 + o];
    o16[o] = fmaxf(t, 0.f);
  }
}

__global__ __launch_bounds__(256) void final_kernel(
    const float* __restrict__ hgA, const float* __restrict__ hgB, const float* __restrict__ aW1,
    const float* __restrict__ ab1, const float* __restrict__ aW2, const float* __restrict__ ab2,
    const float* __restrict__ mW, const float* __restrict__ mb, const float* __restrict__ fcW1,
    const float* __restrict__ fcb1, const float* __restrict__ fcW2,
    const float* __restrict__ fcb2, float* __restrict__ out, int ng) {
  int g = blockIdx.x * blockDim.x + threadIdx.x;
  if (g >= ng) return;
  float hi[16], hj[16];
#pragma unroll
  for (int k = 0; k < 16; k++) {
    hi[k] = hgA[g * 16 + k];
    hj[k] = hgB[g * 16 + k];
  }
  float AB[16], AA[16], BB[16];
  efn_dev(hi, hj, aW1, ab1, aW2, ab2, mW, mb, AB);
  efn_dev(hi, hi, aW1, ab1, aW2, ab2, mW, mb, AA);
  efn_dev(hj, hj, aW1, ab1, aW2, ab2, mW, mb, BB);
  float t8[8];
#pragma unroll
  for (int o = 0; o < 8; o++) {
    float t = fcb1[o];
#pragma unroll
    for (int k = 0; k < 16; k++) t += AB[k] * fcW1[k * 8 + o];
    t8[o] = fmaxf(t, 0.f);
  }
  float sc = fcb2[0];
#pragma unroll
  for (int o = 0; o < 8; o++) sc += t8[o] * fcW2[o];
  out[g] = sc;
#pragma unroll
  for (int k = 0; k < 16; k++) out[ng + g * 16 + k] = AB[k] - BB[k];
#pragma unroll
  for (int k = 0; k < 16; k++) out[ng + ng * 16 + g * 16 + k] = AB[k] - AA[k];
}

// ---------------- Launch ----------------

extern "C" void kernel_launch(void* const* d_in, const int* in_sizes, int n_in, void* d_out,
                              int out_size, void* d_ws, size_t ws_size, hipStream_t stream) {
  (void)n_in;
  (void)out_size;
  (void)ws_size;
  const int N = in_sizes[0] / 64;
  const int E = in_sizes[2] / 2;
  const int NG = NGRAPH;

  char* w = (char*)d_ws;
  auto alloc = [&](size_t bytes) -> void* {
    void* p = (void*)w;
    w += (bytes + 255) & ~(size_t)255;
    return p;
  };
  int* row_ptr = (int*)alloc((size_t)(N + 1) * 4);
  int* row_fill = (int*)alloc((size_t)N * 4);
  int* col = (int*)alloc((size_t)E * 4);
  int* blockSums = (int*)alloc(1024 * 4);
  int* blockOffs = (int*)alloc(1024 * 4);
  float* x1 = (float*)alloc((size_t)N * 64 * 4);
  float* x2 = (float*)alloc((size_t)N * 32 * 4);
  float* x3 = (float*)alloc((size_t)N * 16 * 4);
  float* stats = (float*)alloc(3 * 256 * 4);
  float* cnt = (float*)alloc((size_t)NG * 4);
  float* summ = (float*)alloc((size_t)NG * 16 * 4);
  float* cvals = (float*)alloc((size_t)NG * 16 * 4);
  float* hgA = (float*)alloc((size_t)NG * 16 * 4);
  float* hgB = (float*)alloc((size_t)NG * 16 * 4);

  const float* attW = (const float*)d_in[27];
  const float* attb = (const float*)d_in[28];

  for (int s = 0; s < 2; s++) {
    const float* x0 = (const float*)d_in[s];
    const int* esrc = (const int*)d_in[2 + s];
    const int* edst = esrc + E;
    const int* batch = (const int*)d_in[4 + s];
    float* hg = s ? hgB : hgA;

    // CSR by dst (reused for all 3 layers)
    hipMemsetAsync(row_fill, 0, (size_t)N * 4, stream);
    hist_kernel<<<2048, 256, 0, stream>>>(edst, E, row_fill);
    int NB = (N + SCAN_BLOCK - 1) / SCAN_BLOCK;
    scan_block_sums<<<NB, SCAN_BLOCK, 0, stream>>>(row_fill, N, blockSums);
    scan_offsets<<<1, SCAN_BLOCK, 0, stream>>>(blockSums, NB, blockOffs);
    scan_apply<<<NB, SCAN_BLOCK, 0, stream>>>(row_fill, N, blockOffs, row_ptr, E);
    hipMemsetAsync(row_fill, 0, (size_t)N * 4, stream);
    fill_kernel<<<2048, 256, 0, stream>>>(esrc, edst, E, row_ptr, row_fill, col);

    hipMemsetAsync(stats, 0, 3 * 256 * 4, stream);
    // layer 1: 64 -> 64 -> 64
    gin_kernel<64, 64, 64, 4><<<2048, 256, 0, stream>>>(
        x0, row_ptr, col, (const float*)d_in[6], (const float*)d_in[7], (const float*)d_in[8],
        (const float*)d_in[9], (const float*)d_in[10], x1, stats, N);
    bn_kernel<<<2048, 256, 0, stream>>>(x1, stats, (const float*)d_in[11],
                                        (const float*)d_in[12], N * 64, 63, 1.0f / (float)N);
    // layer 2: 64 -> 32 -> 32
    gin_kernel<64, 32, 32, 4><<<2048, 256, 0, stream>>>(
        x1, row_ptr, col, (const float*)d_in[13], (const float*)d_in[14], (const float*)d_in[15],
        (const float*)d_in[16], (const float*)d_in[17], x2, stats + 256, N);
    bn_kernel<<<2048, 256, 0, stream>>>(x2, stats + 256, (const float*)d_in[18],
                                        (const float*)d_in[19], N * 32, 31, 1.0f / (float)N);
    // layer 3: 32 -> 16 -> 16
    gin_kernel<32, 16, 16, 8><<<2048, 256, 0, stream>>>(
        x2, row_ptr, col, (const float*)d_in[20], (const float*)d_in[21], (const float*)d_in[22],
        (const float*)d_in[23], (const float*)d_in[24], x3, stats + 512, N);
    bn_kernel<<<2048, 256, 0, stream>>>(x3, stats + 512, (const float*)d_in[25],
                                        (const float*)d_in[26], N * 16, 15, 1.0f / (float)N);

    // readout
    hipMemsetAsync(cnt, 0, (size_t)NG * 4, stream);
    hipMemsetAsync(summ, 0, (size_t)NG * 16 * 4, stream);
    hipMemsetAsync(hg, 0, (size_t)NG * 16 * 4, stream);
    readout_sums<<<2048, 256, 0, stream>>>(x3, batch, cnt, summ, N);
    readout_c<<<(NG * 16 + 255) / 256, 256, 0, stream>>>(cnt, summ, attW, attb, cvals, NG);
    readout_pool<<<2048, 256, 0, stream>>>(x3, batch, cvals, hg, N);
  }

  final_kernel<<<(NG + 255) / 256, 256, 0, stream>>>(
      hgA, hgB, (const float*)d_in[29], (const float*)d_in[30], (const float*)d_in[31],
      (const float*)d_in[32], (const float*)d_in[33], (const float*)d_in[34],
      (const float*)d_in[35], (const float*)d_in[36], (const float*)d_in[37],
      (const float*)d_in[38], (float*)d_out, NG);
}

// Round 2
// 3267.605 us; speedup vs baseline: 1.3524x; 1.3524x over previous
//
#include <hip/hip_runtime.h>
#include <math.h>

#define NGRAPH 1000
#define SCAN_BLOCK 1024

// ---------------- CSR build ----------------

__global__ __launch_bounds__(256) void hist_kernel(const int* __restrict__ dst, int E,
                                                   int* __restrict__ counts) {
  for (int e = blockIdx.x * blockDim.x + threadIdx.x; e < E; e += gridDim.x * blockDim.x)
    atomicAdd(&counts[dst[e]], 1);
}

__global__ __launch_bounds__(SCAN_BLOCK) void scan_block_sums(const int* __restrict__ counts, int n,
                                                              int* __restrict__ blockSums) {
  __shared__ int s[SCAN_BLOCK];
  int i = blockIdx.x * SCAN_BLOCK + threadIdx.x;
  s[threadIdx.x] = (i < n) ? counts[i] : 0;
  __syncthreads();
  for (int off = SCAN_BLOCK / 2; off > 0; off >>= 1) {
    if (threadIdx.x < off) s[threadIdx.x] += s[threadIdx.x + off];
    __syncthreads();
  }
  if (threadIdx.x == 0) blockSums[blockIdx.x] = s[0];
}

__global__ __launch_bounds__(SCAN_BLOCK) void scan_offsets(const int* __restrict__ blockSums, int nb,
                                                           int* __restrict__ blockOffs) {
  __shared__ int s[SCAN_BLOCK];
  int v = (threadIdx.x < nb) ? blockSums[threadIdx.x] : 0;
  s[threadIdx.x] = v;
  __syncthreads();
  for (int off = 1; off < SCAN_BLOCK; off <<= 1) {
    int t = (threadIdx.x >= off) ? s[threadIdx.x - off] : 0;
    __syncthreads();
    s[threadIdx.x] += t;
    __syncthreads();
  }
  if (threadIdx.x < nb) blockOffs[threadIdx.x] = s[threadIdx.x] - v;  // exclusive
}

__global__ __launch_bounds__(SCAN_BLOCK) void scan_apply(const int* __restrict__ counts, int n,
                                                         const int* __restrict__ blockOffs,
                                                         int* __restrict__ row_ptr, int total) {
  __shared__ int s[SCAN_BLOCK];
  int i = blockIdx.x * SCAN_BLOCK + threadIdx.x;
  int v = (i < n) ? counts[i] : 0;
  s[threadIdx.x] = v;
  __syncthreads();
  for (int off = 1; off < SCAN_BLOCK; off <<= 1) {
    int t = (threadIdx.x >= off) ? s[threadIdx.x - off] : 0;
    __syncthreads();
    s[threadIdx.x] += t;
    __syncthreads();
  }
  if (i < n) row_ptr[i] = blockOffs[blockIdx.x] + s[threadIdx.x] - v;
  if (i == 0) row_ptr[n] = total;
}

__global__ __launch_bounds__(256) void fill_kernel(const int* __restrict__ src,
                                                   const int* __restrict__ dst, int E,
                                                   const int* __restrict__ row_ptr,
                                                   int* __restrict__ row_fill,
                                                   int* __restrict__ col) {
  for (int e = blockIdx.x * blockDim.x + threadIdx.x; e < E; e += gridDim.x * blockDim.x) {
    int d = dst[e];
    int pos = atomicAdd(&row_fill[d], 1);
    col[row_ptr[d] + pos] = src[e];
  }
}

// ---------------- Aggregation (latency-optimized gather) ----------------
// lane = float4 chunk of features; LPN = FIN/4 lanes per node.
// Optionally folds the previous layer's BatchNorm (per-feature affine) into the
// aggregation: agg(BN(h)) = s * agg_raw(h) + (beta - s*mu) * (1+eps+deg).

template <int FIN, bool HAS_BN>
__global__ __launch_bounds__(256) void agg_kernel(
    const float* __restrict__ x, const int* __restrict__ row_ptr, const int* __restrict__ col,
    const float* __restrict__ epsp, const float* __restrict__ stats,
    const float* __restrict__ gamma, const float* __restrict__ beta, float invN,
    float* __restrict__ out, int n) {
  constexpr int LPN = FIN / 4;
  constexpr int NPB = 256 / LPN;
  const int tid = threadIdx.x;
  const int ln = tid / LPN;
  const int fl = tid % LPN;
  const float e1 = 1.0f + epsp[0];

  float s0 = 1.f, s1 = 1.f, s2 = 1.f, s3 = 1.f;
  float o0 = 0.f, o1 = 0.f, o2 = 0.f, o3 = 0.f;
  if (HAS_BN) {
    int f = fl * 4;
    float mu0 = stats[f + 0] * invN, mu1 = stats[f + 1] * invN;
    float mu2 = stats[f + 2] * invN, mu3 = stats[f + 3] * invN;
    float v0 = stats[128 + f + 0] * invN - mu0 * mu0;
    float v1 = stats[128 + f + 1] * invN - mu1 * mu1;
    float v2 = stats[128 + f + 2] * invN - mu2 * mu2;
    float v3 = stats[128 + f + 3] * invN - mu3 * mu3;
    s0 = gamma[f + 0] * rsqrtf(v0 + 1e-5f);
    s1 = gamma[f + 1] * rsqrtf(v1 + 1e-5f);
    s2 = gamma[f + 2] * rsqrtf(v2 + 1e-5f);
    s3 = gamma[f + 3] * rsqrtf(v3 + 1e-5f);
    o0 = beta[f + 0] - s0 * mu0;
    o1 = beta[f + 1] - s1 * mu1;
    o2 = beta[f + 2] - s2 * mu2;
    o3 = beta[f + 3] - s3 * mu3;
  }

  const float4* xr = (const float4*)x;
  int node = blockIdx.x * NPB + ln;
  if (node >= n) return;
  const int rs = row_ptr[node], re = row_ptr[node + 1];
  const int deg = re - rs;

  float4 self = xr[(size_t)node * LPN + fl];
  float ax = e1 * self.x, ay = e1 * self.y, az = e1 * self.z, aw = e1 * self.w;

  int e = rs;
  for (; e + 4 <= re; e += 4) {
    int c0 = col[e], c1 = col[e + 1], c2 = col[e + 2], c3 = col[e + 3];
    float4 v0 = xr[(size_t)c0 * LPN + fl];
    float4 v1 = xr[(size_t)c1 * LPN + fl];
    float4 v2 = xr[(size_t)c2 * LPN + fl];
    float4 v3 = xr[(size_t)c3 * LPN + fl];
    ax += (v0.x + v1.x) + (v2.x + v3.x);
    ay += (v0.y + v1.y) + (v2.y + v3.y);
    az += (v0.z + v1.z) + (v2.z + v3.z);
    aw += (v0.w + v1.w) + (v2.w + v3.w);
  }
  for (; e < re; e++) {
    float4 v = xr[(size_t)col[e] * LPN + fl];
    ax += v.x;
    ay += v.y;
    az += v.z;
    aw += v.w;
  }

  float4 r;
  if (HAS_BN) {
    const float dfac = e1 + (float)deg;
    r.x = s0 * ax + o0 * dfac;
    r.y = s1 * ay + o1 * dfac;
    r.z = s2 * az + o2 * dfac;
    r.w = s3 * aw + o3 * dfac;
  } else {
    r.x = ax;
    r.y = ay;
    r.z = az;
    r.w = aw;
  }
  ((float4*)out)[(size_t)node * LPN + fl] = r;
}

// ---------------- MLP (Lin-ReLU-Lin) + BN-stat partials ----------------

template <int FIN, int FMID, int FOUT, int NPB>
__global__ __launch_bounds__(FIN * NPB) void mlp_kernel(
    const float* __restrict__ agg, const float* __restrict__ W1, const float* __restrict__ b1,
    const float* __restrict__ W2, const float* __restrict__ b2, float* __restrict__ out,
    float* __restrict__ stats, int n) {
  __shared__ float W1s[FIN * FMID];
  __shared__ float W2s[FMID * FOUT];
  __shared__ float b1s[FMID];
  __shared__ float b2s[FOUT];
  __shared__ float hbuf[NPB][FIN];
  __shared__ float mbuf[NPB][FMID];
  const int tid = threadIdx.x;
  for (int i = tid; i < FIN * FMID; i += blockDim.x) W1s[i] = W1[i];
  for (int i = tid; i < FMID * FOUT; i += blockDim.x) W2s[i] = W2[i];
  if (tid < FMID) b1s[tid] = b1[tid];
  if (tid < FOUT) b2s[tid] = b2[tid];
  __syncthreads();

  const int ln = tid / FIN;
  const int f = tid % FIN;
  float ssum = 0.f, ssq = 0.f;

  for (int base = blockIdx.x * NPB; base < n; base += gridDim.x * NPB) {
    int node = base + ln;
    bool valid = node < n;
    hbuf[ln][f] = valid ? agg[(size_t)node * FIN + f] : 0.f;
    __syncthreads();
    if (f < FMID) {
      float m = b1s[f];
#pragma unroll 8
      for (int k = 0; k < FIN; k++) m += hbuf[ln][k] * W1s[k * FMID + f];
      mbuf[ln][f] = fmaxf(m, 0.f);
    }
    __syncthreads();
    if (f < FOUT) {
      float o = b2s[f];
#pragma unroll 8
      for (int k = 0; k < FMID; k++) o += mbuf[ln][k] * W2s[k * FOUT + f];
      if (valid) {
        out[(size_t)node * FOUT + f] = o;
        ssum += o;
        ssq += o * o;
      }
    }
    __syncthreads();
  }

  if (f < FOUT) hbuf[ln][f] = ssum;
  __syncthreads();
  if (tid < FOUT) {
    float t = 0.f;
    for (int l = 0; l < NPB; l++) t += hbuf[l][tid];
    atomicAdd(&stats[tid], t);
  }
  __syncthreads();
  if (f < FOUT) hbuf[ln][f] = ssq;
  __syncthreads();
  if (tid < FOUT) {
    float t = 0.f;
    for (int l = 0; l < NPB; l++) t += hbuf[l][tid];
    atomicAdd(&stats[128 + tid], t);
  }
}

// ---------------- BatchNorm apply (in place) ----------------

__global__ __launch_bounds__(256) void bn_kernel(float* __restrict__ x,
                                                 const float* __restrict__ stats,
                                                 const float* __restrict__ gamma,
                                                 const float* __restrict__ beta, int total,
                                                 int fmask, float invN) {
  for (int idx = blockIdx.x * blockDim.x + threadIdx.x; idx < total;
       idx += gridDim.x * blockDim.x) {
    int g = idx & fmask;
    float mu = stats[g] * invN;
    float var = stats[128 + g] * invN - mu * mu;
    float sc = gamma[g] * rsqrtf(var + 1e-5f);
    x[idx] = (x[idx] - mu) * sc + beta[g];
  }
}

// ---------------- Readout ----------------

__global__ __launch_bounds__(256) void readout_sums(const float* __restrict__ x3,
                                                    const int* __restrict__ batch,
                                                    float* __restrict__ cnt,
                                                    float* __restrict__ summ, int n) {
  int total = n * 16;
  for (int idx = blockIdx.x * blockDim.x + threadIdx.x; idx < total;
       idx += gridDim.x * blockDim.x) {
    int node = idx >> 4;
    int f = idx & 15;
    int g = batch[node];
    atomicAdd(&summ[g * 16 + f], x3[idx]);
    if (f == 0) atomicAdd(&cnt[g], 1.0f);
  }
}

__global__ __launch_bounds__(256) void readout_c(const float* __restrict__ cnt,
                                                 const float* __restrict__ summ,
                                                 const float* __restrict__ attW,
                                                 const float* __restrict__ attb,
                                                 float* __restrict__ cvals, int ng) {
  int idx = blockIdx.x * blockDim.x + threadIdx.x;
  if (idx >= ng * 16) return;
  int g = idx >> 4;
  int fo = idx & 15;
  float inv = 1.0f / fmaxf(cnt[g], 1.0f);
  float acc = attb[fo];
  for (int k = 0; k < 16; k++) acc += (summ[g * 16 + k] * inv) * attW[k * 16 + fo];
  cvals[idx] = 1.0f / (1.0f + expf(-acc));
}

__global__ __launch_bounds__(256) void readout_pool(const float* __restrict__ x3,
                                                    const int* __restrict__ batch,
                                                    const float* __restrict__ cvals,
                                                    float* __restrict__ hg, int n) {
  int total = n * 16;
  for (int idx = blockIdx.x * blockDim.x + threadIdx.x; idx < total;
       idx += gridDim.x * blockDim.x) {
    int node = idx >> 4;
    int f = idx & 15;
    int g = batch[node];
    float xv = x3[idx];
    float p = xv * cvals[g * 16 + f];
    for (int m = 8; m >= 1; m >>= 1) p += __shfl_xor(p, m, 16);
    float gate = 1.0f / (1.0f + expf(-p));
    atomicAdd(&hg[g * 16 + f], gate * xv);
  }
}

// ---------------- EFN + final ----------------

__device__ inline void efn_dev(const float* hi, const float* hj, const float* aW1,
                               const float* ab1, const float* aW2, const float* ab2,
                               const float* mW, const float* mb, float* o16) {
  float h[32];
#pragma unroll
  for (int k = 0; k < 16; k++) {
    h[k] = hi[k];
    h[16 + k] = hj[k];
  }
  float m8[8];
#pragma unroll
  for (int o = 0; o < 8; o++) {
    float t = ab1[o];
#pragma unroll
    for (int k = 0; k < 32; k++) t += h[k] * aW1[k * 8 + o];
    m8[o] = fmaxf(t, 0.f);
  }
  float enc[32];
#pragma unroll
  for (int o = 0; o < 32; o++) {
    float t = ab2[o];
#pragma unroll
    for (int k = 0; k < 8; k++) t += m8[k] * aW2[k * 32 + o];
    float att = tanhf(t);
    enc[o] = att * h[o] + h[o];
  }
#pragma unroll
  for (int o = 0; o < 16; o++) {
    float t = mb[o];
#pragma unroll
    for (int k = 0; k < 32; k++) t += enc[k] * mW[k * 16 + o];
    o16[o] = fmaxf(t, 0.f);
  }
}

__global__ __launch_bounds__(256) void final_kernel(
    const float* __restrict__ hgA, const float* __restrict__ hgB, const float* __restrict__ aW1,
    const float* __restrict__ ab1, const float* __restrict__ aW2, const float* __restrict__ ab2,
    const float* __restrict__ mW, const float* __restrict__ mb, const float* __restrict__ fcW1,
    const float* __restrict__ fcb1, const float* __restrict__ fcW2,
    const float* __restrict__ fcb2, float* __restrict__ out, int ng) {
  int g = blockIdx.x * blockDim.x + threadIdx.x;
  if (g >= ng) return;
  float hi[16], hj[16];
#pragma unroll
  for (int k = 0; k < 16; k++) {
    hi[k] = hgA[g * 16 + k];
    hj[k] = hgB[g * 16 + k];
  }
  float AB[16], AA[16], BB[16];
  efn_dev(hi, hj, aW1, ab1, aW2, ab2, mW, mb, AB);
  efn_dev(hi, hi, aW1, ab1, aW2, ab2, mW, mb, AA);
  efn_dev(hj, hj, aW1, ab1, aW2, ab2, mW, mb, BB);
  float t8[8];
#pragma unroll
  for (int o = 0; o < 8; o++) {
    float t = fcb1[o];
#pragma unroll
    for (int k = 0; k < 16; k++) t += AB[k] * fcW1[k * 8 + o];
    t8[o] = fmaxf(t, 0.f);
  }
  float sc = fcb2[0];
#pragma unroll
  for (int o = 0; o < 8; o++) sc += t8[o] * fcW2[o];
  out[g] = sc;
#pragma unroll
  for (int k = 0; k < 16; k++) out[ng + g * 16 + k] = AB[k] - BB[k];
#pragma unroll
  for (int k = 0; k < 16; k++) out[ng + ng * 16 + g * 16 + k] = AB[k] - AA[k];
}

// ---------------- Launch ----------------

extern "C" void kernel_launch(void* const* d_in, const int* in_sizes, int n_in, void* d_out,
                              int out_size, void* d_ws, size_t ws_size, hipStream_t stream) {
  (void)n_in;
  (void)out_size;
  (void)ws_size;
  const int N = in_sizes[0] / 64;
  const int E = in_sizes[2] / 2;
  const int NG = NGRAPH;

  char* w = (char*)d_ws;
  auto alloc = [&](size_t bytes) -> void* {
    void* p = (void*)w;
    w += (bytes + 255) & ~(size_t)255;
    return p;
  };
  int* row_ptr = (int*)alloc((size_t)(N + 1) * 4);
  int* row_fill = (int*)alloc((size_t)N * 4);
  int* col = (int*)alloc((size_t)E * 4);
  int* blockSums = (int*)alloc(1024 * 4);
  int* blockOffs = (int*)alloc(1024 * 4);
  float* aggbuf = (float*)alloc((size_t)N * 64 * 4);   // shared agg staging (64-wide max)
  float* xbuf = (float*)alloc((size_t)N * 64 * 4);     // holds x1, then x2, then x3 (aliased)
  float* stats = (float*)alloc(3 * 256 * 4);
  float* cnt = (float*)alloc((size_t)NG * 4);
  float* summ = (float*)alloc((size_t)NG * 16 * 4);
  float* cvals = (float*)alloc((size_t)NG * 16 * 4);
  float* hgA = (float*)alloc((size_t)NG * 16 * 4);
  float* hgB = (float*)alloc((size_t)NG * 16 * 4);

  float* x1 = xbuf;                      // N*64, live until layer-2 agg done
  float* x2 = xbuf;                      // N*32, overwrites x1 after layer-2 agg (safe: mlp
                                         // reads aggbuf only)
  float* x3 = xbuf + (size_t)N * 32;     // N*16, disjoint from x2

  const float* attW = (const float*)d_in[27];
  const float* attb = (const float*)d_in[28];
  const float invN = 1.0f / (float)N;

  for (int s = 0; s < 2; s++) {
    const float* x0 = (const float*)d_in[s];
    const int* esrc = (const int*)d_in[2 + s];
    const int* edst = esrc + E;
    const int* batch = (const int*)d_in[4 + s];
    float* hg = s ? hgB : hgA;

    // CSR by dst (reused for all 3 layers)
    hipMemsetAsync(row_fill, 0, (size_t)N * 4, stream);
    hist_kernel<<<2048, 256, 0, stream>>>(edst, E, row_fill);
    int NB = (N + SCAN_BLOCK - 1) / SCAN_BLOCK;
    scan_block_sums<<<NB, SCAN_BLOCK, 0, stream>>>(row_fill, N, blockSums);
    scan_offsets<<<1, SCAN_BLOCK, 0, stream>>>(blockSums, NB, blockOffs);
    scan_apply<<<NB, SCAN_BLOCK, 0, stream>>>(row_fill, N, blockOffs, row_ptr, E);
    hipMemsetAsync(row_fill, 0, (size_t)N * 4, stream);
    fill_kernel<<<2048, 256, 0, stream>>>(esrc, edst, E, row_ptr, row_fill, col);

    hipMemsetAsync(stats, 0, 3 * 256 * 4, stream);

    // layer 1: agg(x0) -> mlp 64->64->64 (raw h1 + stats)
    agg_kernel<64, false><<<(N + 15) / 16, 256, 0, stream>>>(
        x0, row_ptr, col, (const float*)d_in[6], nullptr, nullptr, nullptr, invN, aggbuf, N);
    mlp_kernel<64, 64, 64, 4><<<2048, 256, 0, stream>>>(
        aggbuf, (const float*)d_in[7], (const float*)d_in[8], (const float*)d_in[9],
        (const float*)d_in[10], x1, stats, N);

    // layer 2: agg(BN1(h1)) -> mlp 64->32->32 (raw h2 + stats)
    agg_kernel<64, true><<<(N + 15) / 16, 256, 0, stream>>>(
        x1, row_ptr, col, (const float*)d_in[13], stats, (const float*)d_in[11],
        (const float*)d_in[12], invN, aggbuf, N);
    mlp_kernel<64, 32, 32, 4><<<2048, 256, 0, stream>>>(
        aggbuf, (const float*)d_in[14], (const float*)d_in[15], (const float*)d_in[16],
        (const float*)d_in[17], x2, stats + 256, N);

    // layer 3: agg(BN2(h2)) -> mlp 32->16->16 (raw h3 + stats)
    agg_kernel<32, true><<<(N + 31) / 32, 256, 0, stream>>>(
        x2, row_ptr, col, (const float*)d_in[20], stats + 256, (const float*)d_in[18],
        (const float*)d_in[19], invN, aggbuf, N);
    mlp_kernel<32, 16, 16, 8><<<2048, 256, 0, stream>>>(
        aggbuf, (const float*)d_in[21], (const float*)d_in[22], (const float*)d_in[23],
        (const float*)d_in[24], x3, stats + 512, N);
    // BN3 applied explicitly (x3 is consumed twice by readout)
    bn_kernel<<<2048, 256, 0, stream>>>(x3, stats + 512, (const float*)d_in[25],
                                        (const float*)d_in[26], N * 16, 15, invN);

    // readout
    hipMemsetAsync(cnt, 0, (size_t)NG * 4, stream);
    hipMemsetAsync(summ, 0, (size_t)NG * 16 * 4, stream);
    hipMemsetAsync(hg, 0, (size_t)NG * 16 * 4, stream);
    readout_sums<<<2048, 256, 0, stream>>>(x3, batch, cnt, summ, N);
    readout_c<<<(NG * 16 + 255) / 256, 256, 0, stream>>>(cnt, summ, attW, attb, cvals, NG);
    readout_pool<<<2048, 256, 0, stream>>>(x3, batch, cvals, hg, N);
  }

  final_kernel<<<(NG + 255) / 256, 256, 0, stream>>>(
      hgA, hgB, (const float*)d_in[29], (const float*)d_in[30], (const float*)d_in[31],
      (const float*)d_in[32], (const float*)d_in[33], (const float*)d_in[34],
      (const float*)d_in[35], (const float*)d_in[36], (const float*)d_in[37],
      (const float*)d_in[38], (float*)d_out, NG);
}

// Round 3
// 2653.531 us; speedup vs baseline: 1.6654x; 1.2314x over previous
//
#include <hip/hip_runtime.h>
#include <math.h>

#define NGRAPH 1000
#define SCAN_BLOCK 1024

// ---------------- CSR build ----------------

__global__ __launch_bounds__(256) void hist_kernel(const int* __restrict__ dst, int E,
                                                   int* __restrict__ counts) {
  for (int e = blockIdx.x * blockDim.x + threadIdx.x; e < E; e += gridDim.x * blockDim.x)
    atomicAdd(&counts[dst[e]], 1);
}

__global__ __launch_bounds__(SCAN_BLOCK) void scan_block_sums(const int* __restrict__ counts, int n,
                                                              int* __restrict__ blockSums) {
  __shared__ int s[SCAN_BLOCK];
  int i = blockIdx.x * SCAN_BLOCK + threadIdx.x;
  s[threadIdx.x] = (i < n) ? counts[i] : 0;
  __syncthreads();
  for (int off = SCAN_BLOCK / 2; off > 0; off >>= 1) {
    if (threadIdx.x < off) s[threadIdx.x] += s[threadIdx.x + off];
    __syncthreads();
  }
  if (threadIdx.x == 0) blockSums[blockIdx.x] = s[0];
}

__global__ __launch_bounds__(SCAN_BLOCK) void scan_offsets(const int* __restrict__ blockSums, int nb,
                                                           int* __restrict__ blockOffs) {
  __shared__ int s[SCAN_BLOCK];
  int v = (threadIdx.x < nb) ? blockSums[threadIdx.x] : 0;
  s[threadIdx.x] = v;
  __syncthreads();
  for (int off = 1; off < SCAN_BLOCK; off <<= 1) {
    int t = (threadIdx.x >= off) ? s[threadIdx.x - off] : 0;
    __syncthreads();
    s[threadIdx.x] += t;
    __syncthreads();
  }
  if (threadIdx.x < nb) blockOffs[threadIdx.x] = s[threadIdx.x] - v;  // exclusive
}

__global__ __launch_bounds__(SCAN_BLOCK) void scan_apply(const int* __restrict__ counts, int n,
                                                         const int* __restrict__ blockOffs,
                                                         int* __restrict__ row_ptr, int total) {
  __shared__ int s[SCAN_BLOCK];
  int i = blockIdx.x * SCAN_BLOCK + threadIdx.x;
  int v = (i < n) ? counts[i] : 0;
  s[threadIdx.x] = v;
  __syncthreads();
  for (int off = 1; off < SCAN_BLOCK; off <<= 1) {
    int t = (threadIdx.x >= off) ? s[threadIdx.x - off] : 0;
    __syncthreads();
    s[threadIdx.x] += t;
    __syncthreads();
  }
  if (i < n) row_ptr[i] = blockOffs[blockIdx.x] + s[threadIdx.x] - v;
  if (i == 0) row_ptr[n] = total;
}

__global__ __launch_bounds__(256) void fill_kernel(const int* __restrict__ src,
                                                   const int* __restrict__ dst, int E,
                                                   const int* __restrict__ row_ptr,
                                                   int* __restrict__ row_fill,
                                                   int* __restrict__ col) {
  for (int e = blockIdx.x * blockDim.x + threadIdx.x; e < E; e += gridDim.x * blockDim.x) {
    int d = dst[e];
    int pos = atomicAdd(&row_fill[d], 1);
    col[row_ptr[d] + pos] = src[e];
  }
}

// ---------------- Streaming linear: y = (optional BN affine)(x) . W ----------------
// Exploits linearity: agg(x).W == agg(x.W), so W1 is applied BEFORE the gather,
// shrinking the gather width (64/32/16 instead of 64/64/32).

template <int FIN, int FOUT, bool HAS_BN>
__global__ __launch_bounds__(256) void lin_kernel(const float* __restrict__ x,
                                                  const float* __restrict__ W,
                                                  const float* __restrict__ stats,
                                                  const float* __restrict__ gamma,
                                                  const float* __restrict__ beta, float invN,
                                                  float* __restrict__ y, int n) {
  constexpr int L = (FIN > FOUT) ? FIN : FOUT;
  constexpr int NPB = 256 / L;
  __shared__ float Ws[FIN * FOUT];
  __shared__ float xb[NPB][FIN + 1];
  const int tid = threadIdx.x;
  for (int i = tid; i < FIN * FOUT; i += 256) Ws[i] = W[i];
  const int ln = tid / L;
  const int f = tid % L;
  float scv = 1.f, ofv = 0.f;
  if (HAS_BN && f < FIN) {
    float mu = stats[f] * invN;
    float var = stats[128 + f] * invN - mu * mu;
    scv = gamma[f] * rsqrtf(var + 1e-5f);
    ofv = beta[f] - scv * mu;
  }
  __syncthreads();
  for (int base = blockIdx.x * NPB; base < n; base += gridDim.x * NPB) {
    int node = base + ln;
    bool valid = node < n;
    if (f < FIN) xb[ln][f] = valid ? fmaf(x[(size_t)node * FIN + f], scv, ofv) : 0.f;
    __syncthreads();
    if (f < FOUT && valid) {
      float acc = 0.f;
#pragma unroll 8
      for (int k = 0; k < FIN; k++) acc += xb[ln][k] * Ws[k * FOUT + f];
      y[(size_t)node * FOUT + f] = acc;
    }
    __syncthreads();
  }
}

// ---------------- Gather: m = ReLU((1+eps)*y_i + sum_j y_j + b1) ----------------

template <int F>
__global__ __launch_bounds__(256) void aggrelu_kernel(const float* __restrict__ y,
                                                      const int* __restrict__ row_ptr,
                                                      const int* __restrict__ col,
                                                      const float* __restrict__ epsp,
                                                      const float* __restrict__ b1,
                                                      float* __restrict__ out, int n) {
  constexpr int LPN = F / 4;
  constexpr int NPB = 256 / LPN;
  const int tid = threadIdx.x;
  const int ln = tid / LPN;
  const int fl = tid % LPN;
  const float e1 = 1.0f + epsp[0];
  const float4 bv = ((const float4*)b1)[fl];

  int node = blockIdx.x * NPB + ln;
  if (node >= n) return;
  const float4* xr = (const float4*)y;
  const int rs = row_ptr[node], re = row_ptr[node + 1];

  float4 self = xr[(size_t)node * LPN + fl];
  float ax = e1 * self.x, ay = e1 * self.y, az = e1 * self.z, aw = e1 * self.w;

  int e = rs;
  for (; e + 4 <= re; e += 4) {
    int c0 = col[e], c1 = col[e + 1], c2 = col[e + 2], c3 = col[e + 3];
    float4 v0 = xr[(size_t)c0 * LPN + fl];
    float4 v1 = xr[(size_t)c1 * LPN + fl];
    float4 v2 = xr[(size_t)c2 * LPN + fl];
    float4 v3 = xr[(size_t)c3 * LPN + fl];
    ax += (v0.x + v1.x) + (v2.x + v3.x);
    ay += (v0.y + v1.y) + (v2.y + v3.y);
    az += (v0.z + v1.z) + (v2.z + v3.z);
    aw += (v0.w + v1.w) + (v2.w + v3.w);
  }
  for (; e < re; e++) {
    float4 v = xr[(size_t)col[e] * LPN + fl];
    ax += v.x;
    ay += v.y;
    az += v.z;
    aw += v.w;
  }

  float4 r;
  r.x = fmaxf(ax + bv.x, 0.f);
  r.y = fmaxf(ay + bv.y, 0.f);
  r.z = fmaxf(az + bv.z, 0.f);
  r.w = fmaxf(aw + bv.w, 0.f);
  ((float4*)out)[(size_t)node * LPN + fl] = r;
}

// ---------------- Second linear + bias + BN-stat partials ----------------

template <int F, int NPB>
__global__ __launch_bounds__(F * NPB) void lin2s_kernel(const float* __restrict__ m,
                                                        const float* __restrict__ W,
                                                        const float* __restrict__ b,
                                                        float* __restrict__ h,
                                                        float* __restrict__ stats, int n) {
  __shared__ float Ws[F * F];
  __shared__ float bs[F];
  __shared__ float xb[NPB][F + 1];
  const int tid = threadIdx.x;
  for (int i = tid; i < F * F; i += F * NPB) Ws[i] = W[i];
  if (tid < F) bs[tid] = b[tid];
  __syncthreads();
  const int ln = tid / F;
  const int f = tid % F;
  float ssum = 0.f, ssq = 0.f;

  for (int base = blockIdx.x * NPB; base < n; base += gridDim.x * NPB) {
    int node = base + ln;
    bool valid = node < n;
    xb[ln][f] = valid ? m[(size_t)node * F + f] : 0.f;
    __syncthreads();
    float acc = bs[f];
#pragma unroll 8
    for (int k = 0; k < F; k++) acc += xb[ln][k] * Ws[k * F + f];
    if (valid) {
      h[(size_t)node * F + f] = acc;
      ssum += acc;
      ssq += acc * acc;
    }
    __syncthreads();
  }

  xb[ln][f] = ssum;
  __syncthreads();
  if (tid < F) {
    float t = 0.f;
    for (int l = 0; l < NPB; l++) t += xb[l][tid];
    atomicAdd(&stats[tid], t);
  }
  __syncthreads();
  xb[ln][f] = ssq;
  __syncthreads();
  if (tid < F) {
    float t = 0.f;
    for (int l = 0; l < NPB; l++) t += xb[l][tid];
    atomicAdd(&stats[128 + tid], t);
  }
}

// ---------------- BatchNorm apply (in place) ----------------

__global__ __launch_bounds__(256) void bn_kernel(float* __restrict__ x,
                                                 const float* __restrict__ stats,
                                                 const float* __restrict__ gamma,
                                                 const float* __restrict__ beta, int total,
                                                 int fmask, float invN) {
  for (int idx = blockIdx.x * blockDim.x + threadIdx.x; idx < total;
       idx += gridDim.x * blockDim.x) {
    int g = idx & fmask;
    float mu = stats[g] * invN;
    float var = stats[128 + g] * invN - mu * mu;
    float sc = gamma[g] * rsqrtf(var + 1e-5f);
    x[idx] = (x[idx] - mu) * sc + beta[g];
  }
}

// ---------------- Readout ----------------

__global__ __launch_bounds__(256) void readout_sums(const float* __restrict__ x3,
                                                    const int* __restrict__ batch,
                                                    float* __restrict__ cnt,
                                                    float* __restrict__ summ, int n) {
  int total = n * 16;
  for (int idx = blockIdx.x * blockDim.x + threadIdx.x; idx < total;
       idx += gridDim.x * blockDim.x) {
    int node = idx >> 4;
    int f = idx & 15;
    int g = batch[node];
    atomicAdd(&summ[g * 16 + f], x3[idx]);
    if (f == 0) atomicAdd(&cnt[g], 1.0f);
  }
}

__global__ __launch_bounds__(256) void readout_c(const float* __restrict__ cnt,
                                                 const float* __restrict__ summ,
                                                 const float* __restrict__ attW,
                                                 const float* __restrict__ attb,
                                                 float* __restrict__ cvals, int ng) {
  int idx = blockIdx.x * blockDim.x + threadIdx.x;
  if (idx >= ng * 16) return;
  int g = idx >> 4;
  int fo = idx & 15;
  float inv = 1.0f / fmaxf(cnt[g], 1.0f);
  float acc = attb[fo];
  for (int k = 0; k < 16; k++) acc += (summ[g * 16 + k] * inv) * attW[k * 16 + fo];
  cvals[idx] = 1.0f / (1.0f + expf(-acc));
}

__global__ __launch_bounds__(256) void readout_pool(const float* __restrict__ x3,
                                                    const int* __restrict__ batch,
                                                    const float* __restrict__ cvals,
                                                    float* __restrict__ hg, int n) {
  int total = n * 16;
  for (int idx = blockIdx.x * blockDim.x + threadIdx.x; idx < total;
       idx += gridDim.x * blockDim.x) {
    int node = idx >> 4;
    int f = idx & 15;
    int g = batch[node];
    float xv = x3[idx];
    float p = xv * cvals[g * 16 + f];
    for (int m = 8; m >= 1; m >>= 1) p += __shfl_xor(p, m, 16);
    float gate = 1.0f / (1.0f + expf(-p));
    atomicAdd(&hg[g * 16 + f], gate * xv);
  }
}

// ---------------- EFN + final: 16 lanes per graph, weights + vectors in LDS ----------------
// Replaces the one-graph-per-thread version whose 150+ live floats spilled to
// scratch (677 us at 0.12% VALUBusy). LDS rows padded (33/17/9) to break
// cross-graph bank aliasing.

__global__ __launch_bounds__(256) void final3_kernel(
    const float* __restrict__ hgA, const float* __restrict__ hgB, const float* __restrict__ aW1,
    const float* __restrict__ ab1, const float* __restrict__ aW2, const float* __restrict__ ab2,
    const float* __restrict__ mW, const float* __restrict__ mb, const float* __restrict__ fcW1,
    const float* __restrict__ fcb1, const float* __restrict__ fcW2,
    const float* __restrict__ fcb2, float* __restrict__ out, int ng) {
  __shared__ float aW1s[256], aW2s[256], mWs[512], fcW1s[128];
  __shared__ float ab1s[8], ab2s[32], mbs[16], fcb1s[8], fcW2s[8];
  __shared__ float fcb2s;
  __shared__ float hb[16][33], m8b[16][9], encb[16][33], abb[16][17], tb[16][9];
  const int tid = threadIdx.x;
  aW1s[tid] = aW1[tid];
  aW2s[tid] = aW2[tid];
  mWs[tid] = mW[tid];
  mWs[256 + tid] = mW[256 + tid];
  if (tid < 128) fcW1s[tid] = fcW1[tid];
  if (tid < 8) {
    ab1s[tid] = ab1[tid];
    fcb1s[tid] = fcb1[tid];
    fcW2s[tid] = fcW2[tid];
  }
  if (tid < 32) ab2s[tid] = ab2[tid];
  if (tid < 16) mbs[tid] = mb[tid];
  if (tid == 0) fcb2s = fcb2[0];
  __syncthreads();

  const int g = tid >> 4;
  const int l = tid & 15;
  const int gg = blockIdx.x * 16 + g;
  const bool valid = gg < ng;
  const float hiv = valid ? hgA[gg * 16 + l] : 0.f;
  const float hjv = valid ? hgB[gg * 16 + l] : 0.f;
  float res[3];

#pragma unroll
  for (int p = 0; p < 3; p++) {
    // p=0: (hi,hj)  p=1: (hi,hi)  p=2: (hj,hj)
    float ha = (p == 2) ? hjv : hiv;
    float h2 = (p == 1) ? hiv : hjv;
    hb[g][l] = ha;
    hb[g][16 + l] = h2;
    __syncthreads();
    if (l < 8) {
      float t = ab1s[l];
#pragma unroll
      for (int k = 0; k < 32; k++) t += hb[g][k] * aW1s[k * 8 + l];
      m8b[g][l] = fmaxf(t, 0.f);
    }
    __syncthreads();
    float e0 = ab2s[l], e1 = ab2s[16 + l];
#pragma unroll
    for (int k = 0; k < 8; k++) {
      float mv = m8b[g][k];
      e0 += mv * aW2s[k * 32 + l];
      e1 += mv * aW2s[k * 32 + 16 + l];
    }
    float a0 = tanhf(e0), a1 = tanhf(e1);
    encb[g][l] = fmaf(a0, ha, ha);
    encb[g][16 + l] = fmaf(a1, h2, h2);
    __syncthreads();
    float o = mbs[l];
#pragma unroll
    for (int k = 0; k < 32; k++) o += encb[g][k] * mWs[k * 16 + l];
    res[p] = fmaxf(o, 0.f);
    __syncthreads();
  }

  if (valid) {
    out[ng + gg * 16 + l] = res[0] - res[2];              // h_Ab = AB - BB
    out[ng + ng * 16 + gg * 16 + l] = res[0] - res[1];    // h_aB = AB - AA
  }
  abb[g][l] = res[0];
  __syncthreads();
  if (l < 8) {
    float t = fcb1s[l];
#pragma unroll
    for (int k = 0; k < 16; k++) t += abb[g][k] * fcW1s[k * 8 + l];
    tb[g][l] = fmaxf(t, 0.f);
  }
  __syncthreads();
  if (l == 0 && valid) {
    float sc = fcb2s;
#pragma unroll
    for (int o = 0; o < 8; o++) sc += tb[g][o] * fcW2s[o];
    out[gg] = sc;
  }
}

// ---------------- Launch ----------------

extern "C" void kernel_launch(void* const* d_in, const int* in_sizes, int n_in, void* d_out,
                              int out_size, void* d_ws, size_t ws_size, hipStream_t stream) {
  (void)n_in;
  (void)out_size;
  (void)ws_size;
  const int N = in_sizes[0] / 64;
  const int E = in_sizes[2] / 2;
  const int NG = NGRAPH;

  char* w = (char*)d_ws;
  auto alloc = [&](size_t bytes) -> void* {
    void* p = (void*)w;
    w += (bytes + 255) & ~(size_t)255;
    return p;
  };
  int* row_ptr = (int*)alloc((size_t)(N + 1) * 4);
  int* row_fill = (int*)alloc((size_t)N * 4);
  int* col = (int*)alloc((size_t)E * 4);
  int* blockSums = (int*)alloc(1024 * 4);
  int* blockOffs = (int*)alloc(1024 * 4);
  float* bufA = (float*)alloc((size_t)N * 64 * 4);
  float* bufB = (float*)alloc((size_t)N * 64 * 4);
  float* stats = (float*)alloc(3 * 256 * 4);
  float* cnt = (float*)alloc((size_t)NG * 4);
  float* summ = (float*)alloc((size_t)NG * 16 * 4);
  float* cvals = (float*)alloc((size_t)NG * 16 * 4);
  float* hgA = (float*)alloc((size_t)NG * 16 * 4);
  float* hgB = (float*)alloc((size_t)NG * 16 * 4);

  const float* attW = (const float*)d_in[27];
  const float* attb = (const float*)d_in[28];
  const float invN = 1.0f / (float)N;

  for (int s = 0; s < 2; s++) {
    const float* x0 = (const float*)d_in[s];
    const int* esrc = (const int*)d_in[2 + s];
    const int* edst = esrc + E;
    const int* batch = (const int*)d_in[4 + s];
    float* hg = s ? hgB : hgA;

    // CSR by dst (reused for all 3 layers)
    hipMemsetAsync(row_fill, 0, (size_t)N * 4, stream);
    hist_kernel<<<2048, 256, 0, stream>>>(edst, E, row_fill);
    int NB = (N + SCAN_BLOCK - 1) / SCAN_BLOCK;
    scan_block_sums<<<NB, SCAN_BLOCK, 0, stream>>>(row_fill, N, blockSums);
    scan_offsets<<<1, SCAN_BLOCK, 0, stream>>>(blockSums, NB, blockOffs);
    scan_apply<<<NB, SCAN_BLOCK, 0, stream>>>(row_fill, N, blockOffs, row_ptr, E);
    hipMemsetAsync(row_fill, 0, (size_t)N * 4, stream);
    fill_kernel<<<2048, 256, 0, stream>>>(esrc, edst, E, row_ptr, row_fill, col);

    hipMemsetAsync(stats, 0, 3 * 256 * 4, stream);

    // ---- layer 1: y1 = x0.W1 ; m1 = ReLU(agg(y1)+b1) ; h1 = m1.W2+b2 (+stats0) ----
    lin_kernel<64, 64, false><<<2048, 256, 0, stream>>>(
        x0, (const float*)d_in[7], nullptr, nullptr, nullptr, invN, bufA, N);
    aggrelu_kernel<64><<<(N + 15) / 16, 256, 0, stream>>>(
        bufA, row_ptr, col, (const float*)d_in[6], (const float*)d_in[8], bufB, N);
    lin2s_kernel<64, 4><<<2048, 256, 0, stream>>>(bufB, (const float*)d_in[9],
                                                  (const float*)d_in[10], bufA, stats, N);

    // ---- layer 2: y2 = BN1(h1).W1 (64->32) ; m2 ; h2 (+stats1) ----
    lin_kernel<64, 32, true><<<2048, 256, 0, stream>>>(
        bufA, (const float*)d_in[14], stats, (const float*)d_in[11], (const float*)d_in[12],
        invN, bufB, N);
    aggrelu_kernel<32><<<(N + 31) / 32, 256, 0, stream>>>(
        bufB, row_ptr, col, (const float*)d_in[13], (const float*)d_in[15], bufA, N);
    lin2s_kernel<32, 8><<<2048, 256, 0, stream>>>(bufA, (const float*)d_in[16],
                                                  (const float*)d_in[17], bufB, stats + 256, N);

    // ---- layer 3: y3 = BN2(h2).W1 (32->16) ; m3 ; h3 (+stats2) ----
    lin_kernel<32, 16, true><<<2048, 256, 0, stream>>>(
        bufB, (const float*)d_in[21], stats + 256, (const float*)d_in[18],
        (const float*)d_in[19], invN, bufA, N);
    aggrelu_kernel<16><<<(N + 63) / 64, 256, 0, stream>>>(
        bufA, row_ptr, col, (const float*)d_in[20], (const float*)d_in[22], bufB, N);
    lin2s_kernel<16, 16><<<2048, 256, 0, stream>>>(bufB, (const float*)d_in[23],
                                                   (const float*)d_in[24], bufA, stats + 512, N);
    // x3 = BN3(h3), in place on bufA
    bn_kernel<<<2048, 256, 0, stream>>>(bufA, stats + 512, (const float*)d_in[25],
                                        (const float*)d_in[26], N * 16, 15, invN);

    // readout
    hipMemsetAsync(cnt, 0, (size_t)NG * 4, stream);
    hipMemsetAsync(summ, 0, (size_t)NG * 16 * 4, stream);
    hipMemsetAsync(hg, 0, (size_t)NG * 16 * 4, stream);
    readout_sums<<<2048, 256, 0, stream>>>(bufA, batch, cnt, summ, N);
    readout_c<<<(NG * 16 + 255) / 256, 256, 0, stream>>>(cnt, summ, attW, attb, cvals, NG);
    readout_pool<<<2048, 256, 0, stream>>>(bufA, batch, cvals, hg, N);
  }

  final3_kernel<<<(NG + 15) / 16, 256, 0, stream>>>(
      hgA, hgB, (const float*)d_in[29], (const float*)d_in[30], (const float*)d_in[31],
      (const float*)d_in[32], (const float*)d_in[33], (const float*)d_in[34],
      (const float*)d_in[35], (const float*)d_in[36], (const float*)d_in[37],
      (const float*)d_in[38], (float*)d_out, NG);
}

// Round 4
// 2154.140 us; speedup vs baseline: 2.0514x; 1.2318x over previous
//
#include <hip/hip_runtime.h>
#include <math.h>

#define NGRAPH 1000
#define SCAN_BLOCK 1024

// ---------------- CSR build ----------------

__global__ __launch_bounds__(256) void hist_kernel(const int* __restrict__ dst, int E,
                                                   int* __restrict__ counts) {
  for (int e = blockIdx.x * blockDim.x + threadIdx.x; e < E; e += gridDim.x * blockDim.x)
    atomicAdd(&counts[dst[e]], 1);
}

__global__ __launch_bounds__(SCAN_BLOCK) void scan_block_sums(const int* __restrict__ counts, int n,
                                                              int* __restrict__ blockSums) {
  __shared__ int s[SCAN_BLOCK];
  int i = blockIdx.x * SCAN_BLOCK + threadIdx.x;
  s[threadIdx.x] = (i < n) ? counts[i] : 0;
  __syncthreads();
  for (int off = SCAN_BLOCK / 2; off > 0; off >>= 1) {
    if (threadIdx.x < off) s[threadIdx.x] += s[threadIdx.x + off];
    __syncthreads();
  }
  if (threadIdx.x == 0) blockSums[blockIdx.x] = s[0];
}

__global__ __launch_bounds__(SCAN_BLOCK) void scan_offsets(const int* __restrict__ blockSums, int nb,
                                                           int* __restrict__ blockOffs) {
  __shared__ int s[SCAN_BLOCK];
  int v = (threadIdx.x < nb) ? blockSums[threadIdx.x] : 0;
  s[threadIdx.x] = v;
  __syncthreads();
  for (int off = 1; off < SCAN_BLOCK; off <<= 1) {
    int t = (threadIdx.x >= off) ? s[threadIdx.x - off] : 0;
    __syncthreads();
    s[threadIdx.x] += t;
    __syncthreads();
  }
  if (threadIdx.x < nb) blockOffs[threadIdx.x] = s[threadIdx.x] - v;  // exclusive
}

__global__ __launch_bounds__(SCAN_BLOCK) void scan_apply(const int* __restrict__ counts, int n,
                                                         const int* __restrict__ blockOffs,
                                                         int* __restrict__ row_ptr, int total) {
  __shared__ int s[SCAN_BLOCK];
  int i = blockIdx.x * SCAN_BLOCK + threadIdx.x;
  int v = (i < n) ? counts[i] : 0;
  s[threadIdx.x] = v;
  __syncthreads();
  for (int off = 1; off < SCAN_BLOCK; off <<= 1) {
    int t = (threadIdx.x >= off) ? s[threadIdx.x - off] : 0;
    __syncthreads();
    s[threadIdx.x] += t;
    __syncthreads();
  }
  if (i < n) row_ptr[i] = blockOffs[blockIdx.x] + s[threadIdx.x] - v;
  if (i == 0) row_ptr[n] = total;
}

__global__ __launch_bounds__(256) void fill_kernel(const int* __restrict__ src,
                                                   const int* __restrict__ dst, int E,
                                                   const int* __restrict__ row_ptr,
                                                   int* __restrict__ row_fill,
                                                   int* __restrict__ col) {
  for (int e = blockIdx.x * blockDim.x + threadIdx.x; e < E; e += gridDim.x * blockDim.x) {
    int d = dst[e];
    int pos = atomicAdd(&row_fill[d], 1);
    col[row_ptr[d] + pos] = src[e];
  }
}

// ---------------- Streaming linear: y = (optional BN affine)(x) . W ----------------
// agg(x).W == agg(x.W): W1 applied BEFORE the gather (gather width 64/32/16).

template <int FIN, int FOUT, bool HAS_BN>
__global__ __launch_bounds__(256) void lin_kernel(const float* __restrict__ x,
                                                  const float* __restrict__ W,
                                                  const float* __restrict__ stats,
                                                  const float* __restrict__ gamma,
                                                  const float* __restrict__ beta, float invN,
                                                  float* __restrict__ y, int n) {
  constexpr int L = (FIN > FOUT) ? FIN : FOUT;
  constexpr int NPB = 256 / L;
  __shared__ float Ws[FIN * FOUT];
  __shared__ float xb[NPB][FIN + 1];
  const int tid = threadIdx.x;
  for (int i = tid; i < FIN * FOUT; i += 256) Ws[i] = W[i];
  const int ln = tid / L;
  const int f = tid % L;
  float scv = 1.f, ofv = 0.f;
  if (HAS_BN && f < FIN) {
    float mu = stats[f] * invN;
    float var = stats[128 + f] * invN - mu * mu;
    scv = gamma[f] * rsqrtf(var + 1e-5f);
    ofv = beta[f] - scv * mu;
  }
  __syncthreads();
  for (int base = blockIdx.x * NPB; base < n; base += gridDim.x * NPB) {
    int node = base + ln;
    bool valid = node < n;
    if (f < FIN) xb[ln][f] = valid ? fmaf(x[(size_t)node * FIN + f], scv, ofv) : 0.f;
    __syncthreads();
    if (f < FOUT && valid) {
      float acc = 0.f;
#pragma unroll 8
      for (int k = 0; k < FIN; k++) acc += xb[ln][k] * Ws[k * FOUT + f];
      y[(size_t)node * FOUT + f] = acc;
    }
    __syncthreads();
  }
}

// ---------------- Gather: m = ReLU((1+eps)*y_i + sum_j y_j + b1) ----------------

template <int F>
__global__ __launch_bounds__(256) void aggrelu_kernel(const float* __restrict__ y,
                                                      const int* __restrict__ row_ptr,
                                                      const int* __restrict__ col,
                                                      const float* __restrict__ epsp,
                                                      const float* __restrict__ b1,
                                                      float* __restrict__ out, int n) {
  constexpr int LPN = F / 4;
  constexpr int NPB = 256 / LPN;
  const int tid = threadIdx.x;
  const int ln = tid / LPN;
  const int fl = tid % LPN;
  const float e1 = 1.0f + epsp[0];
  const float4 bv = ((const float4*)b1)[fl];

  int node = blockIdx.x * NPB + ln;
  if (node >= n) return;
  const float4* xr = (const float4*)y;
  const int rs = row_ptr[node], re = row_ptr[node + 1];

  float4 self = xr[(size_t)node * LPN + fl];
  float ax = e1 * self.x, ay = e1 * self.y, az = e1 * self.z, aw = e1 * self.w;

  int e = rs;
  for (; e + 4 <= re; e += 4) {
    int c0 = col[e], c1 = col[e + 1], c2 = col[e + 2], c3 = col[e + 3];
    float4 v0 = xr[(size_t)c0 * LPN + fl];
    float4 v1 = xr[(size_t)c1 * LPN + fl];
    float4 v2 = xr[(size_t)c2 * LPN + fl];
    float4 v3 = xr[(size_t)c3 * LPN + fl];
    ax += (v0.x + v1.x) + (v2.x + v3.x);
    ay += (v0.y + v1.y) + (v2.y + v3.y);
    az += (v0.z + v1.z) + (v2.z + v3.z);
    aw += (v0.w + v1.w) + (v2.w + v3.w);
  }
  for (; e < re; e++) {
    float4 v = xr[(size_t)col[e] * LPN + fl];
    ax += v.x;
    ay += v.y;
    az += v.z;
    aw += v.w;
  }

  float4 r;
  r.x = fmaxf(ax + bv.x, 0.f);
  r.y = fmaxf(ay + bv.y, 0.f);
  r.z = fmaxf(az + bv.z, 0.f);
  r.w = fmaxf(aw + bv.w, 0.f);
  ((float4*)out)[(size_t)node * LPN + fl] = r;
}

// ---------------- Second linear + bias + BN-stat partials ----------------

template <int F, int NPB>
__global__ __launch_bounds__(F * NPB) void lin2s_kernel(const float* __restrict__ m,
                                                        const float* __restrict__ W,
                                                        const float* __restrict__ b,
                                                        float* __restrict__ h,
                                                        float* __restrict__ stats, int n) {
  __shared__ float Ws[F * F];
  __shared__ float bs[F];
  __shared__ float xb[NPB][F + 1];
  const int tid = threadIdx.x;
  for (int i = tid; i < F * F; i += F * NPB) Ws[i] = W[i];
  if (tid < F) bs[tid] = b[tid];
  __syncthreads();
  const int ln = tid / F;
  const int f = tid % F;
  float ssum = 0.f, ssq = 0.f;

  for (int base = blockIdx.x * NPB; base < n; base += gridDim.x * NPB) {
    int node = base + ln;
    bool valid = node < n;
    xb[ln][f] = valid ? m[(size_t)node * F + f] : 0.f;
    __syncthreads();
    float acc = bs[f];
#pragma unroll 8
    for (int k = 0; k < F; k++) acc += xb[ln][k] * Ws[k * F + f];
    if (valid) {
      h[(size_t)node * F + f] = acc;
      ssum += acc;
      ssq += acc * acc;
    }
    __syncthreads();
  }

  xb[ln][f] = ssum;
  __syncthreads();
  if (tid < F) {
    float t = 0.f;
    for (int l = 0; l < NPB; l++) t += xb[l][tid];
    atomicAdd(&stats[tid], t);
  }
  __syncthreads();
  xb[ln][f] = ssq;
  __syncthreads();
  if (tid < F) {
    float t = 0.f;
    for (int l = 0; l < NPB; l++) t += xb[l][tid];
    atomicAdd(&stats[128 + tid], t);
  }
}

// ---------------- Graph segment starts (batch is sorted) ----------------

__global__ __launch_bounds__(256) void gstart_kernel(const int* __restrict__ batch, int n,
                                                     int* __restrict__ gstart, int ng) {
  int g = blockIdx.x * blockDim.x + threadIdx.x;
  if (g > ng) return;
  int lo = 0, hi = n;
  while (lo < hi) {
    int mid = (lo + hi) >> 1;
    if (batch[mid] < g) lo = mid + 1; else hi = mid;
  }
  gstart[g] = lo;  // lower_bound; gstart[ng] == n
}

// ---------------- Fused readout: BN3-affine + mean + att-c + gated pool ----------------
// One block per graph; segments contiguous (sorted batch) -> zero atomics.
// Replaces readout_sums/readout_c/readout_pool + bn_kernel + 3 memsets.

__global__ __launch_bounds__(256) void readout_fused(
    const float* __restrict__ h3, const int* __restrict__ gstart,
    const float* __restrict__ stats, const float* __restrict__ gamma,
    const float* __restrict__ beta, float invN, const float* __restrict__ attW,
    const float* __restrict__ attb, float* __restrict__ hg, int ng) {
  __shared__ float sM[16], oM[16], red[16][17], meanM[16], cM[16];
  const int tid = threadIdx.x;
  const int g = blockIdx.x;
  const int f = tid & 15, slot = tid >> 4;
  if (tid < 16) {
    float mu = stats[tid] * invN;
    float var = stats[128 + tid] * invN - mu * mu;
    float s = gamma[tid] * rsqrtf(var + 1e-5f);
    sM[tid] = s;
    oM[tid] = beta[tid] - s * mu;
  }
  __syncthreads();
  const int s0 = gstart[g], e0 = gstart[g + 1];
  const float sf = sM[f], of = oM[f];

  float acc = 0.f;
  for (int node = s0 + slot; node < e0; node += 16)
    acc += fmaf(h3[(size_t)node * 16 + f], sf, of);
  red[slot][f] = acc;
  __syncthreads();
  if (tid < 16) {
    float t = 0.f;
    for (int s = 0; s < 16; s++) t += red[s][tid];
    meanM[tid] = t / fmaxf((float)(e0 - s0), 1.f);
  }
  __syncthreads();
  if (tid < 16) {
    float a = attb[tid];
    for (int k = 0; k < 16; k++) a += meanM[k] * attW[k * 16 + tid];
    cM[tid] = 1.f / (1.f + expf(-a));
  }
  __syncthreads();
  const float cf = cM[f];
  float acc2 = 0.f;
  for (int node = s0 + slot; node < e0; node += 16) {
    float xv = fmaf(h3[(size_t)node * 16 + f], sf, of);
    float p = xv * cf;
    for (int m = 8; m >= 1; m >>= 1) p += __shfl_xor(p, m, 16);
    acc2 += xv / (1.f + expf(-p));  // sigmoid(p) * xv
  }
  red[slot][f] = acc2;
  __syncthreads();
  if (tid < 16) {
    float t = 0.f;
    for (int s = 0; s < 16; s++) t += red[s][tid];
    hg[g * 16 + tid] = t;
  }
}

// ---------------- EFN + final: 16 lanes per graph, weights + vectors in LDS ----------------

__global__ __launch_bounds__(256) void final3_kernel(
    const float* __restrict__ hgA, const float* __restrict__ hgB, const float* __restrict__ aW1,
    const float* __restrict__ ab1, const float* __restrict__ aW2, const float* __restrict__ ab2,
    const float* __restrict__ mW, const float* __restrict__ mb, const float* __restrict__ fcW1,
    const float* __restrict__ fcb1, const float* __restrict__ fcW2,
    const float* __restrict__ fcb2, float* __restrict__ out, int ng) {
  __shared__ float aW1s[256], aW2s[256], mWs[512], fcW1s[128];
  __shared__ float ab1s[8], ab2s[32], mbs[16], fcb1s[8], fcW2s[8];
  __shared__ float fcb2s;
  __shared__ float hb[16][33], m8b[16][9], encb[16][33], abb[16][17], tb[16][9];
  const int tid = threadIdx.x;
  aW1s[tid] = aW1[tid];
  aW2s[tid] = aW2[tid];
  mWs[tid] = mW[tid];
  mWs[256 + tid] = mW[256 + tid];
  if (tid < 128) fcW1s[tid] = fcW1[tid];
  if (tid < 8) {
    ab1s[tid] = ab1[tid];
    fcb1s[tid] = fcb1[tid];
    fcW2s[tid] = fcW2[tid];
  }
  if (tid < 32) ab2s[tid] = ab2[tid];
  if (tid < 16) mbs[tid] = mb[tid];
  if (tid == 0) fcb2s = fcb2[0];
  __syncthreads();

  const int g = tid >> 4;
  const int l = tid & 15;
  const int gg = blockIdx.x * 16 + g;
  const bool valid = gg < ng;
  const float hiv = valid ? hgA[gg * 16 + l] : 0.f;
  const float hjv = valid ? hgB[gg * 16 + l] : 0.f;
  float res[3];

#pragma unroll
  for (int p = 0; p < 3; p++) {
    float ha = (p == 2) ? hjv : hiv;
    float h2 = (p == 1) ? hiv : hjv;
    hb[g][l] = ha;
    hb[g][16 + l] = h2;
    __syncthreads();
    if (l < 8) {
      float t = ab1s[l];
#pragma unroll
      for (int k = 0; k < 32; k++) t += hb[g][k] * aW1s[k * 8 + l];
      m8b[g][l] = fmaxf(t, 0.f);
    }
    __syncthreads();
    float e0 = ab2s[l], e1 = ab2s[16 + l];
#pragma unroll
    for (int k = 0; k < 8; k++) {
      float mv = m8b[g][k];
      e0 += mv * aW2s[k * 32 + l];
      e1 += mv * aW2s[k * 32 + 16 + l];
    }
    float a0 = tanhf(e0), a1 = tanhf(e1);
    encb[g][l] = fmaf(a0, ha, ha);
    encb[g][16 + l] = fmaf(a1, h2, h2);
    __syncthreads();
    float o = mbs[l];
#pragma unroll
    for (int k = 0; k < 32; k++) o += encb[g][k] * mWs[k * 16 + l];
    res[p] = fmaxf(o, 0.f);
    __syncthreads();
  }

  if (valid) {
    out[ng + gg * 16 + l] = res[0] - res[2];            // h_Ab = AB - BB
    out[ng + ng * 16 + gg * 16 + l] = res[0] - res[1];  // h_aB = AB - AA
  }
  abb[g][l] = res[0];
  __syncthreads();
  if (l < 8) {
    float t = fcb1s[l];
#pragma unroll
    for (int k = 0; k < 16; k++) t += abb[g][k] * fcW1s[k * 8 + l];
    tb[g][l] = fmaxf(t, 0.f);
  }
  __syncthreads();
  if (l == 0 && valid) {
    float sc = fcb2s;
#pragma unroll
    for (int o = 0; o < 8; o++) sc += tb[g][o] * fcW2s[o];
    out[gg] = sc;
  }
}

// ---------------- Launch ----------------

extern "C" void kernel_launch(void* const* d_in, const int* in_sizes, int n_in, void* d_out,
                              int out_size, void* d_ws, size_t ws_size, hipStream_t stream) {
  (void)n_in;
  (void)out_size;
  (void)ws_size;
  const int N = in_sizes[0] / 64;
  const int E = in_sizes[2] / 2;
  const int NG = NGRAPH;

  char* w = (char*)d_ws;
  auto alloc = [&](size_t bytes) -> void* {
    void* p = (void*)w;
    w += (bytes + 255) & ~(size_t)255;
    return p;
  };
  int* row_ptr = (int*)alloc((size_t)(N + 1) * 4);
  int* row_fill = (int*)alloc((size_t)N * 4);
  int* col = (int*)alloc((size_t)E * 4);
  int* blockSums = (int*)alloc(1024 * 4);
  int* blockOffs = (int*)alloc(1024 * 4);
  float* bufA = (float*)alloc((size_t)N * 64 * 4);
  float* bufB = (float*)alloc((size_t)N * 64 * 4);
  float* stats = (float*)alloc(3 * 256 * 4);
  int* gstart = (int*)alloc((size_t)(NG + 1) * 4);
  float* hgA = (float*)alloc((size_t)NG * 16 * 4);
  float* hgB = (float*)alloc((size_t)NG * 16 * 4);

  const float* attW = (const float*)d_in[27];
  const float* attb = (const float*)d_in[28];
  const float invN = 1.0f / (float)N;

  for (int s = 0; s < 2; s++) {
    const float* x0 = (const float*)d_in[s];
    const int* esrc = (const int*)d_in[2 + s];
    const int* edst = esrc + E;
    const int* batch = (const int*)d_in[4 + s];
    float* hg = s ? hgB : hgA;

    // CSR by dst (reused for all 3 layers)
    hipMemsetAsync(row_fill, 0, (size_t)N * 4, stream);
    hist_kernel<<<2048, 256, 0, stream>>>(edst, E, row_fill);
    int NB = (N + SCAN_BLOCK - 1) / SCAN_BLOCK;
    scan_block_sums<<<NB, SCAN_BLOCK, 0, stream>>>(row_fill, N, blockSums);
    scan_offsets<<<1, SCAN_BLOCK, 0, stream>>>(blockSums, NB, blockOffs);
    scan_apply<<<NB, SCAN_BLOCK, 0, stream>>>(row_fill, N, blockOffs, row_ptr, E);
    hipMemsetAsync(row_fill, 0, (size_t)N * 4, stream);
    fill_kernel<<<2048, 256, 0, stream>>>(esrc, edst, E, row_ptr, row_fill, col);

    hipMemsetAsync(stats, 0, 3 * 256 * 4, stream);

    // ---- layer 1 ----
    lin_kernel<64, 64, false><<<2048, 256, 0, stream>>>(
        x0, (const float*)d_in[7], nullptr, nullptr, nullptr, invN, bufA, N);
    aggrelu_kernel<64><<<(N + 15) / 16, 256, 0, stream>>>(
        bufA, row_ptr, col, (const float*)d_in[6], (const float*)d_in[8], bufB, N);
    lin2s_kernel<64, 4><<<2048, 256, 0, stream>>>(bufB, (const float*)d_in[9],
                                                  (const float*)d_in[10], bufA, stats, N);

    // ---- layer 2 ----
    lin_kernel<64, 32, true><<<2048, 256, 0, stream>>>(
        bufA, (const float*)d_in[14], stats, (const float*)d_in[11], (const float*)d_in[12],
        invN, bufB, N);
    aggrelu_kernel<32><<<(N + 31) / 32, 256, 0, stream>>>(
        bufB, row_ptr, col, (const float*)d_in[13], (const float*)d_in[15], bufA, N);
    lin2s_kernel<32, 8><<<2048, 256, 0, stream>>>(bufA, (const float*)d_in[16],
                                                  (const float*)d_in[17], bufB, stats + 256, N);

    // ---- layer 3 ----
    lin_kernel<32, 16, true><<<2048, 256, 0, stream>>>(
        bufB, (const float*)d_in[21], stats + 256, (const float*)d_in[18],
        (const float*)d_in[19], invN, bufA, N);
    aggrelu_kernel<16><<<(N + 63) / 64, 256, 0, stream>>>(
        bufA, row_ptr, col, (const float*)d_in[20], (const float*)d_in[22], bufB, N);
    lin2s_kernel<16, 16><<<2048, 256, 0, stream>>>(bufB, (const float*)d_in[23],
                                                   (const float*)d_in[24], bufA, stats + 512, N);

    // ---- fused readout (BN3 folded; batch sorted -> segment-parallel, no atomics) ----
    gstart_kernel<<<(NG + 256) / 256, 256, 0, stream>>>(batch, N, gstart, NG);
    readout_fused<<<NG, 256, 0, stream>>>(bufA, gstart, stats + 512, (const float*)d_in[25],
                                          (const float*)d_in[26], invN, attW, attb, hg, NG);
  }

  final3_kernel<<<(NG + 15) / 16, 256, 0, stream>>>(
      hgA, hgB, (const float*)d_in[29], (const float*)d_in[30], (const float*)d_in[31],
      (const float*)d_in[32], (const float*)d_in[33], (const float*)d_in[34],
      (const float*)d_in[35], (const float*)d_in[36], (const float*)d_in[37],
      (const float*)d_in[38], (float*)d_out, NG);
}

// Round 5
// 1952.037 us; speedup vs baseline: 2.2638x; 1.1035x over previous
//
#include <hip/hip_runtime.h>
#include <math.h>

#define NGRAPH 1000
#define NBK_MAX 1568      // buckets of 128 nodes: ceil(200000/128)=1563
#define PART_BLOCKS 128

// ---------------- Bucketed, atomic-free CSR build ----------------
// bucket = dst >> 7 (128 nodes per bucket). Phase A: per-block LDS histograms.
// colscan/scan_small: cross-block prefixes + bucket offsets. partition: scatter
// packed (src,dst) into bucket-sorted ebuf. bucket_csr: per-bucket counting
// sort -> row_ptr + col (contiguous per-bucket writes). No global atomics.

__global__ __launch_bounds__(256) void bucket_hist(const int* __restrict__ dst, int E, int chunk,
                                                   int* __restrict__ hist, int nbk) {
  __shared__ int lh[NBK_MAX];
  for (int i = threadIdx.x; i < nbk; i += 256) lh[i] = 0;
  __syncthreads();
  const int e0 = blockIdx.x * chunk;
  const int e1 = min(E, e0 + chunk);
  for (int e = e0 + threadIdx.x; e < e1; e += 256) atomicAdd(&lh[dst[e] >> 7], 1);
  __syncthreads();
  int* row = hist + (size_t)blockIdx.x * nbk;
  for (int i = threadIdx.x; i < nbk; i += 256) row[i] = lh[i];
}

__global__ __launch_bounds__(256) void colscan(int* __restrict__ hist, int nbk, int nblk,
                                               int* __restrict__ totals) {
  int b = blockIdx.x * 256 + threadIdx.x;
  if (b >= nbk) return;
  int run = 0;
  for (int k = 0; k < nblk; k++) {
    int t = hist[(size_t)k * nbk + b];
    hist[(size_t)k * nbk + b] = run;  // exclusive prefix over blocks
    run += t;
  }
  totals[b] = run;
}

__global__ __launch_bounds__(1024) void scan_small(const int* __restrict__ in, int n,
                                                   int* __restrict__ out) {
  __shared__ int s[2048];
  const int t = threadIdx.x;
  s[t] = (t < n) ? in[t] : 0;
  s[t + 1024] = (t + 1024 < n) ? in[t + 1024] : 0;
  __syncthreads();
  for (int off = 1; off < 2048; off <<= 1) {
    int v0 = (t >= off) ? s[t - off] : 0;
    int v1 = ((t + 1024) >= off) ? s[t + 1024 - off] : 0;
    __syncthreads();
    s[t] += v0;
    s[t + 1024] += v1;
    __syncthreads();
  }
  if (t < n) out[t] = (t == 0) ? 0 : s[t - 1];
  const int u = t + 1024;
  if (u < n) out[u] = s[u - 1];
  if (t == 0) out[n] = s[n - 1];
}

__global__ __launch_bounds__(256) void partition_kernel(const int* __restrict__ src,
                                                        const int* __restrict__ dst, int E,
                                                        int chunk, const int* __restrict__ hist,
                                                        const int* __restrict__ boff,
                                                        uint2* __restrict__ ebuf, int nbk) {
  __shared__ int lbase[NBK_MAX];
  __shared__ int lcur[NBK_MAX];
  const int* row = hist + (size_t)blockIdx.x * nbk;
  for (int i = threadIdx.x; i < nbk; i += 256) {
    lbase[i] = boff[i] + row[i];
    lcur[i] = 0;
  }
  __syncthreads();
  const int e0 = blockIdx.x * chunk;
  const int e1 = min(E, e0 + chunk);
  for (int e = e0 + threadIdx.x; e < e1; e += 256) {
    int d = dst[e];
    int b = d >> 7;
    int pos = lbase[b] + atomicAdd(&lcur[b], 1);
    ebuf[pos] = make_uint2((unsigned)src[e], (unsigned)d);
  }
}

__global__ __launch_bounds__(256) void bucket_csr(const uint2* __restrict__ ebuf,
                                                  const int* __restrict__ boff,
                                                  int* __restrict__ row_ptr, int* __restrict__ col,
                                                  int N, int E) {
  __shared__ int cnt[128], exc[128], cur[128];
  const int b = blockIdx.x;
  const int node0 = b << 7;
  const int nn = min(128, N - node0);
  const int es = boff[b], ee = boff[b + 1];
  const int t = threadIdx.x;
  if (t < 128) cnt[t] = 0;
  __syncthreads();
  for (int e = es + t; e < ee; e += 256) atomicAdd(&cnt[ebuf[e].y & 127], 1);
  __syncthreads();
  if (t < 128) exc[t] = cnt[t];
  __syncthreads();
  for (int off = 1; off < 128; off <<= 1) {
    int v = 0;
    if (t < 128 && t >= off) v = exc[t - off];
    __syncthreads();
    if (t < 128) exc[t] += v;
    __syncthreads();
  }
  if (t < 128) {
    int ex = (t == 0) ? 0 : exc[t - 1];
    cur[t] = ex;
    if (t < nn) row_ptr[node0 + t] = es + ex;
  }
  __syncthreads();
  for (int e = es + t; e < ee; e += 256) {
    uint2 u = ebuf[e];
    int li = (int)(u.y & 127);
    int pos = es + atomicAdd(&cur[li], 1);
    col[pos] = (int)u.x;
  }
  if (b == 0 && t == 0) row_ptr[N] = E;
}

// ---------------- Streaming linear: y = (optional BN affine)(x) . W ----------------
// agg(x).W == agg(x.W): W1 applied BEFORE the gather (gather width 64/32/16).

template <int FIN, int FOUT, bool HAS_BN>
__global__ __launch_bounds__(256) void lin_kernel(const float* __restrict__ x,
                                                  const float* __restrict__ W,
                                                  const float* __restrict__ stats,
                                                  const float* __restrict__ gamma,
                                                  const float* __restrict__ beta, float invN,
                                                  float* __restrict__ y, int n) {
  constexpr int L = (FIN > FOUT) ? FIN : FOUT;
  constexpr int NPB = 256 / L;
  __shared__ float Ws[FIN * FOUT];
  __shared__ float xb[NPB][FIN + 1];
  const int tid = threadIdx.x;
  for (int i = tid; i < FIN * FOUT; i += 256) Ws[i] = W[i];
  const int ln = tid / L;
  const int f = tid % L;
  float scv = 1.f, ofv = 0.f;
  if (HAS_BN && f < FIN) {
    float mu = stats[f] * invN;
    float var = stats[128 + f] * invN - mu * mu;
    scv = gamma[f] * rsqrtf(var + 1e-5f);
    ofv = beta[f] - scv * mu;
  }
  __syncthreads();
  for (int base = blockIdx.x * NPB; base < n; base += gridDim.x * NPB) {
    int node = base + ln;
    bool valid = node < n;
    if (f < FIN) xb[ln][f] = valid ? fmaf(x[(size_t)node * FIN + f], scv, ofv) : 0.f;
    __syncthreads();
    if (f < FOUT && valid) {
      float acc = 0.f;
#pragma unroll 8
      for (int k = 0; k < FIN; k++) acc += xb[ln][k] * Ws[k * FOUT + f];
      y[(size_t)node * FOUT + f] = acc;
    }
    __syncthreads();
  }
}

// ---------------- Gather: m = ReLU((1+eps)*y_i + sum_j y_j + b1) ----------------

template <int F>
__global__ __launch_bounds__(256) void aggrelu_kernel(const float* __restrict__ y,
                                                      const int* __restrict__ row_ptr,
                                                      const int* __restrict__ col,
                                                      const float* __restrict__ epsp,
                                                      const float* __restrict__ b1,
                                                      float* __restrict__ out, int n) {
  constexpr int LPN = F / 4;
  constexpr int NPB = 256 / LPN;
  const int tid = threadIdx.x;
  const int ln = tid / LPN;
  const int fl = tid % LPN;
  const float e1 = 1.0f + epsp[0];
  const float4 bv = ((const float4*)b1)[fl];

  int node = blockIdx.x * NPB + ln;
  if (node >= n) return;
  const float4* xr = (const float4*)y;
  const int rs = row_ptr[node], re = row_ptr[node + 1];

  float4 self = xr[(size_t)node * LPN + fl];
  float ax = e1 * self.x, ay = e1 * self.y, az = e1 * self.z, aw = e1 * self.w;

  int e = rs;
  for (; e + 4 <= re; e += 4) {
    int c0 = col[e], c1 = col[e + 1], c2 = col[e + 2], c3 = col[e + 3];
    float4 v0 = xr[(size_t)c0 * LPN + fl];
    float4 v1 = xr[(size_t)c1 * LPN + fl];
    float4 v2 = xr[(size_t)c2 * LPN + fl];
    float4 v3 = xr[(size_t)c3 * LPN + fl];
    ax += (v0.x + v1.x) + (v2.x + v3.x);
    ay += (v0.y + v1.y) + (v2.y + v3.y);
    az += (v0.z + v1.z) + (v2.z + v3.z);
    aw += (v0.w + v1.w) + (v2.w + v3.w);
  }
  for (; e < re; e++) {
    float4 v = xr[(size_t)col[e] * LPN + fl];
    ax += v.x;
    ay += v.y;
    az += v.z;
    aw += v.w;
  }

  float4 r;
  r.x = fmaxf(ax + bv.x, 0.f);
  r.y = fmaxf(ay + bv.y, 0.f);
  r.z = fmaxf(az + bv.z, 0.f);
  r.w = fmaxf(aw + bv.w, 0.f);
  ((float4*)out)[(size_t)node * LPN + fl] = r;
}

// ---------------- Second linear + bias + BN-stat partials ----------------

template <int F, int NPB>
__global__ __launch_bounds__(F * NPB) void lin2s_kernel(const float* __restrict__ m,
                                                        const float* __restrict__ W,
                                                        const float* __restrict__ b,
                                                        float* __restrict__ h,
                                                        float* __restrict__ stats, int n) {
  __shared__ float Ws[F * F];
  __shared__ float bs[F];
  __shared__ float xb[NPB][F + 1];
  const int tid = threadIdx.x;
  for (int i = tid; i < F * F; i += F * NPB) Ws[i] = W[i];
  if (tid < F) bs[tid] = b[tid];
  __syncthreads();
  const int ln = tid / F;
  const int f = tid % F;
  float ssum = 0.f, ssq = 0.f;

  for (int base = blockIdx.x * NPB; base < n; base += gridDim.x * NPB) {
    int node = base + ln;
    bool valid = node < n;
    xb[ln][f] = valid ? m[(size_t)node * F + f] : 0.f;
    __syncthreads();
    float acc = bs[f];
#pragma unroll 8
    for (int k = 0; k < F; k++) acc += xb[ln][k] * Ws[k * F + f];
    if (valid) {
      h[(size_t)node * F + f] = acc;
      ssum += acc;
      ssq += acc * acc;
    }
    __syncthreads();
  }

  xb[ln][f] = ssum;
  __syncthreads();
  if (tid < F) {
    float t = 0.f;
    for (int l = 0; l < NPB; l++) t += xb[l][tid];
    atomicAdd(&stats[tid], t);
  }
  __syncthreads();
  xb[ln][f] = ssq;
  __syncthreads();
  if (tid < F) {
    float t = 0.f;
    for (int l = 0; l < NPB; l++) t += xb[l][tid];
    atomicAdd(&stats[128 + tid], t);
  }
}

// ---------------- Graph segment starts (batch is sorted) ----------------

__global__ __launch_bounds__(256) void gstart_kernel(const int* __restrict__ batch, int n,
                                                     int* __restrict__ gstart, int ng) {
  int g = blockIdx.x * blockDim.x + threadIdx.x;
  if (g > ng) return;
  int lo = 0, hi = n;
  while (lo < hi) {
    int mid = (lo + hi) >> 1;
    if (batch[mid] < g) lo = mid + 1; else hi = mid;
  }
  gstart[g] = lo;  // lower_bound; gstart[ng] == n
}

// ---------------- Fused readout: BN3-affine + mean + att-c + gated pool ----------------

__global__ __launch_bounds__(256) void readout_fused(
    const float* __restrict__ h3, const int* __restrict__ gstart,
    const float* __restrict__ stats, const float* __restrict__ gamma,
    const float* __restrict__ beta, float invN, const float* __restrict__ attW,
    const float* __restrict__ attb, float* __restrict__ hg, int ng) {
  __shared__ float sM[16], oM[16], red[16][17], meanM[16], cM[16];
  const int tid = threadIdx.x;
  const int g = blockIdx.x;
  const int f = tid & 15, slot = tid >> 4;
  if (tid < 16) {
    float mu = stats[tid] * invN;
    float var = stats[128 + tid] * invN - mu * mu;
    float s = gamma[tid] * rsqrtf(var + 1e-5f);
    sM[tid] = s;
    oM[tid] = beta[tid] - s * mu;
  }
  __syncthreads();
  const int s0 = gstart[g], e0 = gstart[g + 1];
  const float sf = sM[f], of = oM[f];

  float acc = 0.f;
  for (int node = s0 + slot; node < e0; node += 16)
    acc += fmaf(h3[(size_t)node * 16 + f], sf, of);
  red[slot][f] = acc;
  __syncthreads();
  if (tid < 16) {
    float t = 0.f;
    for (int s = 0; s < 16; s++) t += red[s][tid];
    meanM[tid] = t / fmaxf((float)(e0 - s0), 1.f);
  }
  __syncthreads();
  if (tid < 16) {
    float a = attb[tid];
    for (int k = 0; k < 16; k++) a += meanM[k] * attW[k * 16 + tid];
    cM[tid] = 1.f / (1.f + expf(-a));
  }
  __syncthreads();
  const float cf = cM[f];
  float acc2 = 0.f;
  for (int node = s0 + slot; node < e0; node += 16) {
    float xv = fmaf(h3[(size_t)node * 16 + f], sf, of);
    float p = xv * cf;
    for (int m = 8; m >= 1; m >>= 1) p += __shfl_xor(p, m, 16);
    acc2 += xv / (1.f + expf(-p));  // sigmoid(p) * xv
  }
  red[slot][f] = acc2;
  __syncthreads();
  if (tid < 16) {
    float t = 0.f;
    for (int s = 0; s < 16; s++) t += red[s][tid];
    hg[g * 16 + tid] = t;
  }
}

// ---------------- EFN + final: 16 lanes per graph, weights + vectors in LDS ----------------

__global__ __launch_bounds__(256) void final3_kernel(
    const float* __restrict__ hgA, const float* __restrict__ hgB, const float* __restrict__ aW1,
    const float* __restrict__ ab1, const float* __restrict__ aW2, const float* __restrict__ ab2,
    const float* __restrict__ mW, const float* __restrict__ mb, const float* __restrict__ fcW1,
    const float* __restrict__ fcb1, const float* __restrict__ fcW2,
    const float* __restrict__ fcb2, float* __restrict__ out, int ng) {
  __shared__ float aW1s[256], aW2s[256], mWs[512], fcW1s[128];
  __shared__ float ab1s[8], ab2s[32], mbs[16], fcb1s[8], fcW2s[8];
  __shared__ float fcb2s;
  __shared__ float hb[16][33], m8b[16][9], encb[16][33], abb[16][17], tb[16][9];
  const int tid = threadIdx.x;
  aW1s[tid] = aW1[tid];
  aW2s[tid] = aW2[tid];
  mWs[tid] = mW[tid];
  mWs[256 + tid] = mW[256 + tid];
  if (tid < 128) fcW1s[tid] = fcW1[tid];
  if (tid < 8) {
    ab1s[tid] = ab1[tid];
    fcb1s[tid] = fcb1[tid];
    fcW2s[tid] = fcW2[tid];
  }
  if (tid < 32) ab2s[tid] = ab2[tid];
  if (tid < 16) mbs[tid] = mb[tid];
  if (tid == 0) fcb2s = fcb2[0];
  __syncthreads();

  const int g = tid >> 4;
  const int l = tid & 15;
  const int gg = blockIdx.x * 16 + g;
  const bool valid = gg < ng;
  const float hiv = valid ? hgA[gg * 16 + l] : 0.f;
  const float hjv = valid ? hgB[gg * 16 + l] : 0.f;
  float res[3];

#pragma unroll
  for (int p = 0; p < 3; p++) {
    float ha = (p == 2) ? hjv : hiv;
    float h2 = (p == 1) ? hiv : hjv;
    hb[g][l] = ha;
    hb[g][16 + l] = h2;
    __syncthreads();
    if (l < 8) {
      float t = ab1s[l];
#pragma unroll
      for (int k = 0; k < 32; k++) t += hb[g][k] * aW1s[k * 8 + l];
      m8b[g][l] = fmaxf(t, 0.f);
    }
    __syncthreads();
    float e0 = ab2s[l], e1 = ab2s[16 + l];
#pragma unroll
    for (int k = 0; k < 8; k++) {
      float mv = m8b[g][k];
      e0 += mv * aW2s[k * 32 + l];
      e1 += mv * aW2s[k * 32 + 16 + l];
    }
    float a0 = tanhf(e0), a1 = tanhf(e1);
    encb[g][l] = fmaf(a0, ha, ha);
    encb[g][16 + l] = fmaf(a1, h2, h2);
    __syncthreads();
    float o = mbs[l];
#pragma unroll
    for (int k = 0; k < 32; k++) o += encb[g][k] * mWs[k * 16 + l];
    res[p] = fmaxf(o, 0.f);
    __syncthreads();
  }

  if (valid) {
    out[ng + gg * 16 + l] = res[0] - res[2];            // h_Ab = AB - BB
    out[ng + ng * 16 + gg * 16 + l] = res[0] - res[1];  // h_aB = AB - AA
  }
  abb[g][l] = res[0];
  __syncthreads();
  if (l < 8) {
    float t = fcb1s[l];
#pragma unroll
    for (int k = 0; k < 16; k++) t += abb[g][k] * fcW1s[k * 8 + l];
    tb[g][l] = fmaxf(t, 0.f);
  }
  __syncthreads();
  if (l == 0 && valid) {
    float sc = fcb2s;
#pragma unroll
    for (int o = 0; o < 8; o++) sc += tb[g][o] * fcW2s[o];
    out[gg] = sc;
  }
}

// ---------------- Launch ----------------

extern "C" void kernel_launch(void* const* d_in, const int* in_sizes, int n_in, void* d_out,
                              int out_size, void* d_ws, size_t ws_size, hipStream_t stream) {
  (void)n_in;
  (void)out_size;
  (void)ws_size;
  const int N = in_sizes[0] / 64;
  const int E = in_sizes[2] / 2;
  const int NG = NGRAPH;
  const int NBK = (N + 127) >> 7;          // 1563 for N=200000 (<= NBK_MAX)
  const int CHUNK = (E + PART_BLOCKS - 1) / PART_BLOCKS;

  char* w = (char*)d_ws;
  auto alloc = [&](size_t bytes) -> void* {
    void* p = (void*)w;
    w += (bytes + 255) & ~(size_t)255;
    return p;
  };
  int* row_ptr = (int*)alloc((size_t)(N + 1) * 4);
  int* col = (int*)alloc((size_t)E * 4);
  int* hist = (int*)alloc((size_t)PART_BLOCKS * NBK * 4);
  int* totals = (int*)alloc((size_t)NBK * 4);
  int* boff = (int*)alloc((size_t)(NBK + 1) * 4);
  float* bufA = (float*)alloc((size_t)N * 64 * 4);
  float* bufB = (float*)alloc((size_t)N * 64 * 4);
  float* stats = (float*)alloc(3 * 256 * 4);
  int* gstart = (int*)alloc((size_t)(NG + 1) * 4);
  float* hgA = (float*)alloc((size_t)NG * 16 * 4);
  float* hgB = (float*)alloc((size_t)NG * 16 * 4);
  uint2* ebuf = (uint2*)bufB;  // 25.6 MB alias; bufB is dead during CSR build

  const float* attW = (const float*)d_in[27];
  const float* attb = (const float*)d_in[28];
  const float invN = 1.0f / (float)N;

  for (int s = 0; s < 2; s++) {
    const float* x0 = (const float*)d_in[s];
    const int* esrc = (const int*)d_in[2 + s];
    const int* edst = esrc + E;
    const int* batch = (const int*)d_in[4 + s];
    float* hg = s ? hgB : hgA;

    // ---- bucketed CSR build (no global atomics) ----
    bucket_hist<<<PART_BLOCKS, 256, 0, stream>>>(edst, E, CHUNK, hist, NBK);
    colscan<<<(NBK + 255) / 256, 256, 0, stream>>>(hist, NBK, PART_BLOCKS, totals);
    scan_small<<<1, 1024, 0, stream>>>(totals, NBK, boff);
    partition_kernel<<<PART_BLOCKS, 256, 0, stream>>>(esrc, edst, E, CHUNK, hist, boff, ebuf,
                                                      NBK);
    bucket_csr<<<NBK, 256, 0, stream>>>(ebuf, boff, row_ptr, col, N, E);

    hipMemsetAsync(stats, 0, 3 * 256 * 4, stream);

    // ---- layer 1 ----
    lin_kernel<64, 64, false><<<2048, 256, 0, stream>>>(
        x0, (const float*)d_in[7], nullptr, nullptr, nullptr, invN, bufA, N);
    aggrelu_kernel<64><<<(N + 15) / 16, 256, 0, stream>>>(
        bufA, row_ptr, col, (const float*)d_in[6], (const float*)d_in[8], bufB, N);
    lin2s_kernel<64, 4><<<2048, 256, 0, stream>>>(bufB, (const float*)d_in[9],
                                                  (const float*)d_in[10], bufA, stats, N);

    // ---- layer 2 ----
    lin_kernel<64, 32, true><<<2048, 256, 0, stream>>>(
        bufA, (const float*)d_in[14], stats, (const float*)d_in[11], (const float*)d_in[12],
        invN, bufB, N);
    aggrelu_kernel<32><<<(N + 31) / 32, 256, 0, stream>>>(
        bufB, row_ptr, col, (const float*)d_in[13], (const float*)d_in[15], bufA, N);
    lin2s_kernel<32, 8><<<2048, 256, 0, stream>>>(bufA, (const float*)d_in[16],
                                                  (const float*)d_in[17], bufB, stats + 256, N);

    // ---- layer 3 ----
    lin_kernel<32, 16, true><<<2048, 256, 0, stream>>>(
        bufB, (const float*)d_in[21], stats + 256, (const float*)d_in[18],
        (const float*)d_in[19], invN, bufA, N);
    aggrelu_kernel<16><<<(N + 63) / 64, 256, 0, stream>>>(
        bufA, row_ptr, col, (const float*)d_in[20], (const float*)d_in[22], bufB, N);
    lin2s_kernel<16, 16><<<2048, 256, 0, stream>>>(bufB, (const float*)d_in[23],
                                                   (const float*)d_in[24], bufA, stats + 512, N);

    // ---- fused readout (BN3 folded; batch sorted -> segment-parallel, no atomics) ----
    gstart_kernel<<<(NG + 256) / 256, 256, 0, stream>>>(batch, N, gstart, NG);
    readout_fused<<<NG, 256, 0, stream>>>(bufA, gstart, stats + 512, (const float*)d_in[25],
                                          (const float*)d_in[26], invN, attW, attb, hg, NG);
  }

  final3_kernel<<<(NG + 15) / 16, 256, 0, stream>>>(
      hgA, hgB, (const float*)d_in[29], (const float*)d_in[30], (const float*)d_in[31],
      (const float*)d_in[32], (const float*)d_in[33], (const float*)d_in[34],
      (const float*)d_in[35], (const float*)d_in[36], (const float*)d_in[37],
      (const float*)d_in[38], (float*)d_out, NG);
}

// Round 6
// 1883.640 us; speedup vs baseline: 2.3460x; 1.0363x over previous
//
#include <hip/hip_runtime.h>
#include <math.h>

#define NGRAPH 1000
#define NBK_MAX 1568      // buckets of 128 nodes: ceil(200000/128)=1563
#define PART_BLOCKS 128

typedef unsigned short ushort_t;

static __device__ inline ushort_t f2bf(float f) {
  unsigned u = __float_as_uint(f);
  u = (u + 0x7fffu + ((u >> 16) & 1u)) >> 16;  // RNE
  return (ushort_t)u;
}

// ---------------- Bucketed, atomic-free CSR build ----------------

__global__ __launch_bounds__(256) void bucket_hist(const int* __restrict__ dst, int E, int chunk,
                                                   int* __restrict__ hist, int nbk) {
  __shared__ int lh[NBK_MAX];
  for (int i = threadIdx.x; i < nbk; i += 256) lh[i] = 0;
  __syncthreads();
  const int e0 = blockIdx.x * chunk;
  const int e1 = min(E, e0 + chunk);
  for (int e = e0 + threadIdx.x; e < e1; e += 256) atomicAdd(&lh[dst[e] >> 7], 1);
  __syncthreads();
  int* row = hist + (size_t)blockIdx.x * nbk;
  for (int i = threadIdx.x; i < nbk; i += 256) row[i] = lh[i];
}

__global__ __launch_bounds__(256) void colscan(int* __restrict__ hist, int nbk, int nblk,
                                               int* __restrict__ totals) {
  int b = blockIdx.x * 256 + threadIdx.x;
  if (b >= nbk) return;
  int run = 0;
  for (int k = 0; k < nblk; k++) {
    int t = hist[(size_t)k * nbk + b];
    hist[(size_t)k * nbk + b] = run;
    run += t;
  }
  totals[b] = run;
}

__global__ __launch_bounds__(1024) void scan_small(const int* __restrict__ in, int n,
                                                   int* __restrict__ out) {
  __shared__ int s[2048];
  const int t = threadIdx.x;
  s[t] = (t < n) ? in[t] : 0;
  s[t + 1024] = (t + 1024 < n) ? in[t + 1024] : 0;
  __syncthreads();
  for (int off = 1; off < 2048; off <<= 1) {
    int v0 = (t >= off) ? s[t - off] : 0;
    int v1 = ((t + 1024) >= off) ? s[t + 1024 - off] : 0;
    __syncthreads();
    s[t] += v0;
    s[t + 1024] += v1;
    __syncthreads();
  }
  if (t < n) out[t] = (t == 0) ? 0 : s[t - 1];
  const int u = t + 1024;
  if (u < n) out[u] = s[u - 1];
  if (t == 0) out[n] = s[n - 1];
}

__global__ __launch_bounds__(256) void partition_kernel(const int* __restrict__ src,
                                                        const int* __restrict__ dst, int E,
                                                        int chunk, const int* __restrict__ hist,
                                                        const int* __restrict__ boff,
                                                        uint2* __restrict__ ebuf, int nbk) {
  __shared__ int lbase[NBK_MAX];
  __shared__ int lcur[NBK_MAX];
  const int* row = hist + (size_t)blockIdx.x * nbk;
  for (int i = threadIdx.x; i < nbk; i += 256) {
    lbase[i] = boff[i] + row[i];
    lcur[i] = 0;
  }
  __syncthreads();
  const int e0 = blockIdx.x * chunk;
  const int e1 = min(E, e0 + chunk);
  for (int e = e0 + threadIdx.x; e < e1; e += 256) {
    int d = dst[e];
    int b = d >> 7;
    int pos = lbase[b] + atomicAdd(&lcur[b], 1);
    ebuf[pos] = make_uint2((unsigned)src[e], (unsigned)d);
  }
}

__global__ __launch_bounds__(256) void bucket_csr(const uint2* __restrict__ ebuf,
                                                  const int* __restrict__ boff,
                                                  int* __restrict__ row_ptr, int* __restrict__ col,
                                                  int N, int E) {
  __shared__ int cnt[128], exc[128], cur[128];
  const int b = blockIdx.x;
  const int node0 = b << 7;
  const int nn = min(128, N - node0);
  const int es = boff[b], ee = boff[b + 1];
  const int t = threadIdx.x;
  if (t < 128) cnt[t] = 0;
  __syncthreads();
  for (int e = es + t; e < ee; e += 256) atomicAdd(&cnt[ebuf[e].y & 127], 1);
  __syncthreads();
  if (t < 128) exc[t] = cnt[t];
  __syncthreads();
  for (int off = 1; off < 128; off <<= 1) {
    int v = 0;
    if (t < 128 && t >= off) v = exc[t - off];
    __syncthreads();
    if (t < 128) exc[t] += v;
    __syncthreads();
  }
  if (t < 128) {
    int ex = (t == 0) ? 0 : exc[t - 1];
    cur[t] = ex;
    if (t < nn) row_ptr[node0 + t] = es + ex;
  }
  __syncthreads();
  for (int e = es + t; e < ee; e += 256) {
    uint2 u = ebuf[e];
    int li = (int)(u.y & 127);
    int pos = es + atomicAdd(&cur[li], 1);
    col[pos] = (int)u.x;
  }
  if (b == 0 && t == 0) row_ptr[N] = E;
}

// ---------------- Streaming linear: y_bf16 = (optional BN affine)(x) . W ----------------
// agg(x).W == agg(x.W): W1 applied BEFORE the gather. Output packed bf16 so the
// gather rows are 2 cache lines instead of 4 (fp32 accumulation everywhere else).

template <int FIN, int FOUT, bool HAS_BN>
__global__ __launch_bounds__(256) void lin_kernel(const float* __restrict__ x,
                                                  const float* __restrict__ W,
                                                  const float* __restrict__ stats,
                                                  const float* __restrict__ gamma,
                                                  const float* __restrict__ beta, float invN,
                                                  ushort_t* __restrict__ y, int n) {
  constexpr int L = (FIN > FOUT) ? FIN : FOUT;
  constexpr int NPB = 256 / L;
  __shared__ float Ws[FIN * FOUT];
  __shared__ float xb[NPB][FIN + 1];
  const int tid = threadIdx.x;
  for (int i = tid; i < FIN * FOUT; i += 256) Ws[i] = W[i];
  const int ln = tid / L;
  const int f = tid % L;
  float scv = 1.f, ofv = 0.f;
  if (HAS_BN && f < FIN) {
    float mu = stats[f] * invN;
    float var = stats[128 + f] * invN - mu * mu;
    scv = gamma[f] * rsqrtf(var + 1e-5f);
    ofv = beta[f] - scv * mu;
  }
  __syncthreads();
  for (int base = blockIdx.x * NPB; base < n; base += gridDim.x * NPB) {
    int node = base + ln;
    bool valid = node < n;
    if (f < FIN) xb[ln][f] = valid ? fmaf(x[(size_t)node * FIN + f], scv, ofv) : 0.f;
    __syncthreads();
    if (f < FOUT && valid) {
      float acc = 0.f;
#pragma unroll 8
      for (int k = 0; k < FIN; k++) acc += xb[ln][k] * Ws[k * FOUT + f];
      y[(size_t)node * FOUT + f] = f2bf(acc);
    }
    __syncthreads();
  }
}

// ---------------- Fused gather + MLP tail ----------------
// m = ReLU((1+eps)*y_i + sum_j y_j + b1)  (y bf16, accum fp32, m in LDS fp32)
// h = m . W2 + b2  (+ BN-stat partials). GEMM hides under gather latency
// (gather phase was 12% VALUBusy standalone).

template <int F>
__global__ __launch_bounds__(256) void aggmlp_kernel(
    const ushort_t* __restrict__ y, const int* __restrict__ row_ptr, const int* __restrict__ col,
    const float* __restrict__ epsp, const float* __restrict__ b1, const float* __restrict__ W2,
    const float* __restrict__ b2, float* __restrict__ h, float* __restrict__ stats, int n) {
  constexpr int LPN = F / 8;        // lanes per node, 16B bf16x8 each
  constexpr int NPB = 256 / LPN;    // nodes per block: 32/64/128
  constexpr int RPB = 256 / F;      // GEMM rows in flight: 4/8/16
  constexpr int NITER = NPB / RPB;  // 8
  __shared__ float W2s[F * F];
  __shared__ float b2s[F];
  __shared__ float mbuf[NPB][F + 1];
  const int tid = threadIdx.x;
  for (int i = tid; i < F * F; i += 256) W2s[i] = W2[i];
  if (tid < F) b2s[tid] = b2[tid];

  const int ln = tid / LPN;
  const int fl = tid % LPN;
  const float e1 = 1.0f + epsp[0];
  const int base = blockIdx.x * NPB;
  const int node = base + ln;

  float acc[8];
#pragma unroll
  for (int j = 0; j < 8; j++) acc[j] = 0.f;

  if (node < n) {
    const uint4* yr = (const uint4*)y;
    const size_t rowi = (size_t)node * LPN + fl;
    uint4 sv = yr[rowi];
    const int rs = row_ptr[node], re = row_ptr[node + 1];

    auto addv = [&](uint4 v) {
      acc[0] += __uint_as_float(v.x << 16);
      acc[1] += __uint_as_float(v.x & 0xffff0000u);
      acc[2] += __uint_as_float(v.y << 16);
      acc[3] += __uint_as_float(v.y & 0xffff0000u);
      acc[4] += __uint_as_float(v.z << 16);
      acc[5] += __uint_as_float(v.z & 0xffff0000u);
      acc[6] += __uint_as_float(v.w << 16);
      acc[7] += __uint_as_float(v.w & 0xffff0000u);
    };

    int e = rs;
    for (; e + 4 <= re; e += 4) {
      int c0 = col[e], c1 = col[e + 1], c2 = col[e + 2], c3 = col[e + 3];
      uint4 v0 = yr[(size_t)c0 * LPN + fl];
      uint4 v1 = yr[(size_t)c1 * LPN + fl];
      uint4 v2 = yr[(size_t)c2 * LPN + fl];
      uint4 v3 = yr[(size_t)c3 * LPN + fl];
      addv(v0);
      addv(v1);
      addv(v2);
      addv(v3);
    }
    for (; e < re; e++) addv(yr[(size_t)col[e] * LPN + fl]);

    // self term + b1 + ReLU
    acc[0] = fmaxf(fmaf(e1, __uint_as_float(sv.x << 16), acc[0]) + b1[fl * 8 + 0], 0.f);
    acc[1] = fmaxf(fmaf(e1, __uint_as_float(sv.x & 0xffff0000u), acc[1]) + b1[fl * 8 + 1], 0.f);
    acc[2] = fmaxf(fmaf(e1, __uint_as_float(sv.y << 16), acc[2]) + b1[fl * 8 + 2], 0.f);
    acc[3] = fmaxf(fmaf(e1, __uint_as_float(sv.y & 0xffff0000u), acc[3]) + b1[fl * 8 + 3], 0.f);
    acc[4] = fmaxf(fmaf(e1, __uint_as_float(sv.z << 16), acc[4]) + b1[fl * 8 + 4], 0.f);
    acc[5] = fmaxf(fmaf(e1, __uint_as_float(sv.z & 0xffff0000u), acc[5]) + b1[fl * 8 + 5], 0.f);
    acc[6] = fmaxf(fmaf(e1, __uint_as_float(sv.w << 16), acc[6]) + b1[fl * 8 + 6], 0.f);
    acc[7] = fmaxf(fmaf(e1, __uint_as_float(sv.w & 0xffff0000u), acc[7]) + b1[fl * 8 + 7], 0.f);
  }
#pragma unroll
  for (int j = 0; j < 8; j++) mbuf[ln][fl * 8 + j] = acc[j];
  __syncthreads();

  // GEMM phase: h = m . W2 + b2, plus BN-stat partials
  const int ln2 = tid / F;
  const int f2 = tid % F;
  float ssum = 0.f, ssq = 0.f;
#pragma unroll
  for (int it = 0; it < NITER; it++) {
    const int nl = it * RPB + ln2;
    const int gnode = base + nl;
    float o = b2s[f2];
#pragma unroll 8
    for (int k = 0; k < F; k++) o += mbuf[nl][k] * W2s[k * F + f2];
    if (gnode < n) {
      h[(size_t)gnode * F + f2] = o;
      ssum += o;
      ssq += o * o;
    }
  }
  __syncthreads();
  mbuf[ln2][f2] = ssum;
  __syncthreads();
  if (tid < F) {
    float t = 0.f;
    for (int l = 0; l < RPB; l++) t += mbuf[l][tid];
    atomicAdd(&stats[tid], t);
  }
  __syncthreads();
  mbuf[ln2][f2] = ssq;
  __syncthreads();
  if (tid < F) {
    float t = 0.f;
    for (int l = 0; l < RPB; l++) t += mbuf[l][tid];
    atomicAdd(&stats[128 + tid], t);
  }
}

// ---------------- Graph segment starts (batch is sorted) ----------------

__global__ __launch_bounds__(256) void gstart_kernel(const int* __restrict__ batch, int n,
                                                     int* __restrict__ gstart, int ng) {
  int g = blockIdx.x * blockDim.x + threadIdx.x;
  if (g > ng) return;
  int lo = 0, hi = n;
  while (lo < hi) {
    int mid = (lo + hi) >> 1;
    if (batch[mid] < g) lo = mid + 1; else hi = mid;
  }
  gstart[g] = lo;
}

// ---------------- Fused readout: BN3-affine + mean + att-c + gated pool ----------------

__global__ __launch_bounds__(256) void readout_fused(
    const float* __restrict__ h3, const int* __restrict__ gstart,
    const float* __restrict__ stats, const float* __restrict__ gamma,
    const float* __restrict__ beta, float invN, const float* __restrict__ attW,
    const float* __restrict__ attb, float* __restrict__ hg, int ng) {
  __shared__ float sM[16], oM[16], red[16][17], meanM[16], cM[16];
  const int tid = threadIdx.x;
  const int g = blockIdx.x;
  const int f = tid & 15, slot = tid >> 4;
  if (tid < 16) {
    float mu = stats[tid] * invN;
    float var = stats[128 + tid] * invN - mu * mu;
    float s = gamma[tid] * rsqrtf(var + 1e-5f);
    sM[tid] = s;
    oM[tid] = beta[tid] - s * mu;
  }
  __syncthreads();
  const int s0 = gstart[g], e0 = gstart[g + 1];
  const float sf = sM[f], of = oM[f];

  float acc = 0.f;
  for (int node = s0 + slot; node < e0; node += 16)
    acc += fmaf(h3[(size_t)node * 16 + f], sf, of);
  red[slot][f] = acc;
  __syncthreads();
  if (tid < 16) {
    float t = 0.f;
    for (int s = 0; s < 16; s++) t += red[s][tid];
    meanM[tid] = t / fmaxf((float)(e0 - s0), 1.f);
  }
  __syncthreads();
  if (tid < 16) {
    float a = attb[tid];
    for (int k = 0; k < 16; k++) a += meanM[k] * attW[k * 16 + tid];
    cM[tid] = 1.f / (1.f + expf(-a));
  }
  __syncthreads();
  const float cf = cM[f];
  float acc2 = 0.f;
  for (int node = s0 + slot; node < e0; node += 16) {
    float xv = fmaf(h3[(size_t)node * 16 + f], sf, of);
    float p = xv * cf;
    for (int m = 8; m >= 1; m >>= 1) p += __shfl_xor(p, m, 16);
    acc2 += xv / (1.f + expf(-p));
  }
  red[slot][f] = acc2;
  __syncthreads();
  if (tid < 16) {
    float t = 0.f;
    for (int s = 0; s < 16; s++) t += red[s][tid];
    hg[g * 16 + tid] = t;
  }
}

// ---------------- EFN + final: 16 lanes per graph, weights + vectors in LDS ----------------

__global__ __launch_bounds__(256) void final3_kernel(
    const float* __restrict__ hgA, const float* __restrict__ hgB, const float* __restrict__ aW1,
    const float* __restrict__ ab1, const float* __restrict__ aW2, const float* __restrict__ ab2,
    const float* __restrict__ mW, const float* __restrict__ mb, const float* __restrict__ fcW1,
    const float* __restrict__ fcb1, const float* __restrict__ fcW2,
    const float* __restrict__ fcb2, float* __restrict__ out, int ng) {
  __shared__ float aW1s[256], aW2s[256], mWs[512], fcW1s[128];
  __shared__ float ab1s[8], ab2s[32], mbs[16], fcb1s[8], fcW2s[8];
  __shared__ float fcb2s;
  __shared__ float hb[16][33], m8b[16][9], encb[16][33], abb[16][17], tb[16][9];
  const int tid = threadIdx.x;
  aW1s[tid] = aW1[tid];
  aW2s[tid] = aW2[tid];
  mWs[tid] = mW[tid];
  mWs[256 + tid] = mW[256 + tid];
  if (tid < 128) fcW1s[tid] = fcW1[tid];
  if (tid < 8) {
    ab1s[tid] = ab1[tid];
    fcb1s[tid] = fcb1[tid];
    fcW2s[tid] = fcW2[tid];
  }
  if (tid < 32) ab2s[tid] = ab2[tid];
  if (tid < 16) mbs[tid] = mb[tid];
  if (tid == 0) fcb2s = fcb2[0];
  __syncthreads();

  const int g = tid >> 4;
  const int l = tid & 15;
  const int gg = blockIdx.x * 16 + g;
  const bool valid = gg < ng;
  const float hiv = valid ? hgA[gg * 16 + l] : 0.f;
  const float hjv = valid ? hgB[gg * 16 + l] : 0.f;
  float res[3];

#pragma unroll
  for (int p = 0; p < 3; p++) {
    float ha = (p == 2) ? hjv : hiv;
    float h2 = (p == 1) ? hiv : hjv;
    hb[g][l] = ha;
    hb[g][16 + l] = h2;
    __syncthreads();
    if (l < 8) {
      float t = ab1s[l];
#pragma unroll
      for (int k = 0; k < 32; k++) t += hb[g][k] * aW1s[k * 8 + l];
      m8b[g][l] = fmaxf(t, 0.f);
    }
    __syncthreads();
    float e0 = ab2s[l], e1 = ab2s[16 + l];
#pragma unroll
    for (int k = 0; k < 8; k++) {
      float mv = m8b[g][k];
      e0 += mv * aW2s[k * 32 + l];
      e1 += mv * aW2s[k * 32 + 16 + l];
    }
    float a0 = tanhf(e0), a1 = tanhf(e1);
    encb[g][l] = fmaf(a0, ha, ha);
    encb[g][16 + l] = fmaf(a1, h2, h2);
    __syncthreads();
    float o = mbs[l];
#pragma unroll
    for (int k = 0; k < 32; k++) o += encb[g][k] * mWs[k * 16 + l];
    res[p] = fmaxf(o, 0.f);
    __syncthreads();
  }

  if (valid) {
    out[ng + gg * 16 + l] = res[0] - res[2];            // h_Ab = AB - BB
    out[ng + ng * 16 + gg * 16 + l] = res[0] - res[1];  // h_aB = AB - AA
  }
  abb[g][l] = res[0];
  __syncthreads();
  if (l < 8) {
    float t = fcb1s[l];
#pragma unroll
    for (int k = 0; k < 16; k++) t += abb[g][k] * fcW1s[k * 8 + l];
    tb[g][l] = fmaxf(t, 0.f);
  }
  __syncthreads();
  if (l == 0 && valid) {
    float sc = fcb2s;
#pragma unroll
    for (int o = 0; o < 8; o++) sc += tb[g][o] * fcW2s[o];
    out[gg] = sc;
  }
}

// ---------------- Launch ----------------

extern "C" void kernel_launch(void* const* d_in, const int* in_sizes, int n_in, void* d_out,
                              int out_size, void* d_ws, size_t ws_size, hipStream_t stream) {
  (void)n_in;
  (void)out_size;
  (void)ws_size;
  const int N = in_sizes[0] / 64;
  const int E = in_sizes[2] / 2;
  const int NG = NGRAPH;
  const int NBK = (N + 127) >> 7;
  const int CHUNK = (E + PART_BLOCKS - 1) / PART_BLOCKS;

  char* w = (char*)d_ws;
  auto alloc = [&](size_t bytes) -> void* {
    void* p = (void*)w;
    w += (bytes + 255) & ~(size_t)255;
    return p;
  };
  int* row_ptr = (int*)alloc((size_t)(N + 1) * 4);
  int* col = (int*)alloc((size_t)E * 4);
  int* hist = (int*)alloc((size_t)PART_BLOCKS * NBK * 4);
  int* totals = (int*)alloc((size_t)NBK * 4);
  int* boff = (int*)alloc((size_t)(NBK + 1) * 4);
  float* bufA = (float*)alloc((size_t)N * 64 * 4);
  float* bufB = (float*)alloc((size_t)N * 64 * 4);
  float* stats = (float*)alloc(3 * 256 * 4);
  int* gstart = (int*)alloc((size_t)(NG + 1) * 4);
  float* hgA = (float*)alloc((size_t)NG * 16 * 4);
  float* hgB = (float*)alloc((size_t)NG * 16 * 4);

  // Aliases (disjoint lifetimes):
  uint2* ebuf = (uint2*)bufB;                          // CSR staging, dead before layer 1
  ushort_t* y1 = (ushort_t*)bufB;                      // N*64 bf16 = 25.6 MB  [L1]
  ushort_t* y2 = (ushort_t*)(bufB + (size_t)N * 32);   // 12.8 MB, disjoint from h2=bufB lo [L2]
  ushort_t* y3 = (ushort_t*)(bufA + (size_t)N * 16);   // 6.4 MB, disjoint from h3=bufA lo [L3]

  const float* attW = (const float*)d_in[27];
  const float* attb = (const float*)d_in[28];
  const float invN = 1.0f / (float)N;

  for (int s = 0; s < 2; s++) {
    const float* x0 = (const float*)d_in[s];
    const int* esrc = (const int*)d_in[2 + s];
    const int* edst = esrc + E;
    const int* batch = (const int*)d_in[4 + s];
    float* hg = s ? hgB : hgA;

    // ---- bucketed CSR build (no global atomics) ----
    bucket_hist<<<PART_BLOCKS, 256, 0, stream>>>(edst, E, CHUNK, hist, NBK);
    colscan<<<(NBK + 255) / 256, 256, 0, stream>>>(hist, NBK, PART_BLOCKS, totals);
    scan_small<<<1, 1024, 0, stream>>>(totals, NBK, boff);
    partition_kernel<<<PART_BLOCKS, 256, 0, stream>>>(esrc, edst, E, CHUNK, hist, boff, ebuf,
                                                      NBK);
    bucket_csr<<<NBK, 256, 0, stream>>>(ebuf, boff, row_ptr, col, N, E);

    hipMemsetAsync(stats, 0, 3 * 256 * 4, stream);

    // ---- layer 1: y1 = x0.W1 (bf16) ; h1 = ReLU(agg(y1)+b1).W2+b2 -> bufA ----
    lin_kernel<64, 64, false><<<2048, 256, 0, stream>>>(
        x0, (const float*)d_in[7], nullptr, nullptr, nullptr, invN, y1, N);
    aggmlp_kernel<64><<<(N + 31) / 32, 256, 0, stream>>>(
        y1, row_ptr, col, (const float*)d_in[6], (const float*)d_in[8], (const float*)d_in[9],
        (const float*)d_in[10], bufA, stats, N);

    // ---- layer 2: y2 = BN1(h1).W1 (bf16) ; h2 -> bufB lo ----
    lin_kernel<64, 32, true><<<2048, 256, 0, stream>>>(
        bufA, (const float*)d_in[14], stats, (const float*)d_in[11], (const float*)d_in[12],
        invN, y2, N);
    aggmlp_kernel<32><<<(N + 63) / 64, 256, 0, stream>>>(
        y2, row_ptr, col, (const float*)d_in[13], (const float*)d_in[15], (const float*)d_in[16],
        (const float*)d_in[17], bufB, stats + 256, N);

    // ---- layer 3: y3 = BN2(h2).W1 (bf16) ; h3 -> bufA lo ----
    lin_kernel<32, 16, true><<<2048, 256, 0, stream>>>(
        bufB, (const float*)d_in[21], stats + 256, (const float*)d_in[18],
        (const float*)d_in[19], invN, y3, N);
    aggmlp_kernel<16><<<(N + 127) / 128, 256, 0, stream>>>(
        y3, row_ptr, col, (const float*)d_in[20], (const float*)d_in[22], (const float*)d_in[23],
        (const float*)d_in[24], bufA, stats + 512, N);

    // ---- fused readout (BN3 folded; batch sorted -> segment-parallel, no atomics) ----
    gstart_kernel<<<(NG + 256) / 256, 256, 0, stream>>>(batch, N, gstart, NG);
    readout_fused<<<NG, 256, 0, stream>>>(bufA, gstart, stats + 512, (const float*)d_in[25],
                                          (const float*)d_in[26], invN, attW, attb, hg, NG);
  }

  final3_kernel<<<(NG + 15) / 16, 256, 0, stream>>>(
      hgA, hgB, (const float*)d_in[29], (const float*)d_in[30], (const float*)d_in[31],
      (const float*)d_in[32], (const float*)d_in[33], (const float*)d_in[34],
      (const float*)d_in[35], (const float*)d_in[36], (const float*)d_in[37],
      (const float*)d_in[38], (float*)d_out, NG);
}

// Round 7
// 1810.355 us; speedup vs baseline: 2.4410x; 1.0405x over previous
//
#include <hip/hip_runtime.h>
#include <math.h>

#define NGRAPH 1000
#define NBK_MAX 1568      // buckets of 128 nodes: ceil(200000/128)=1563
#define PART_BLOCKS 128

typedef unsigned short ushort_t;

static __device__ inline ushort_t f2bf(float f) {
  unsigned u = __float_as_uint(f);
  u = (u + 0x7fffu + ((u >> 16) & 1u)) >> 16;  // RNE
  return (ushort_t)u;
}

// ---------------- Bucketed, atomic-free CSR build ----------------

__global__ __launch_bounds__(256) void bucket_hist(const int* __restrict__ dst, int E, int chunk,
                                                   int* __restrict__ hist, int nbk) {
  __shared__ int lh[NBK_MAX];
  for (int i = threadIdx.x; i < nbk; i += 256) lh[i] = 0;
  __syncthreads();
  const int e0 = blockIdx.x * chunk;
  const int e1 = min(E, e0 + chunk);
  for (int e = e0 + threadIdx.x; e < e1; e += 256) atomicAdd(&lh[dst[e] >> 7], 1);
  __syncthreads();
  int* row = hist + (size_t)blockIdx.x * nbk;
  for (int i = threadIdx.x; i < nbk; i += 256) row[i] = lh[i];
}

__global__ __launch_bounds__(256) void colscan(int* __restrict__ hist, int nbk, int nblk,
                                               int* __restrict__ totals) {
  int b = blockIdx.x * 256 + threadIdx.x;
  if (b >= nbk) return;
  int run = 0;
  for (int k = 0; k < nblk; k++) {
    int t = hist[(size_t)k * nbk + b];
    hist[(size_t)k * nbk + b] = run;
    run += t;
  }
  totals[b] = run;
}

__global__ __launch_bounds__(1024) void scan_small(const int* __restrict__ in, int n,
                                                   int* __restrict__ out) {
  __shared__ int s[2048];
  const int t = threadIdx.x;
  s[t] = (t < n) ? in[t] : 0;
  s[t + 1024] = (t + 1024 < n) ? in[t + 1024] : 0;
  __syncthreads();
  for (int off = 1; off < 2048; off <<= 1) {
    int v0 = (t >= off) ? s[t - off] : 0;
    int v1 = ((t + 1024) >= off) ? s[t + 1024 - off] : 0;
    __syncthreads();
    s[t] += v0;
    s[t + 1024] += v1;
    __syncthreads();
  }
  if (t < n) out[t] = (t == 0) ? 0 : s[t - 1];
  const int u = t + 1024;
  if (u < n) out[u] = s[u - 1];
  if (t == 0) out[n] = s[n - 1];
}

__global__ __launch_bounds__(256) void partition_kernel(const int* __restrict__ src,
                                                        const int* __restrict__ dst, int E,
                                                        int chunk, const int* __restrict__ hist,
                                                        const int* __restrict__ boff,
                                                        uint2* __restrict__ ebuf, int nbk) {
  __shared__ int lbase[NBK_MAX];
  __shared__ int lcur[NBK_MAX];
  const int* row = hist + (size_t)blockIdx.x * nbk;
  for (int i = threadIdx.x; i < nbk; i += 256) {
    lbase[i] = boff[i] + row[i];
    lcur[i] = 0;
  }
  __syncthreads();
  const int e0 = blockIdx.x * chunk;
  const int e1 = min(E, e0 + chunk);
  for (int e = e0 + threadIdx.x; e < e1; e += 256) {
    int d = dst[e];
    int b = d >> 7;
    int pos = lbase[b] + atomicAdd(&lcur[b], 1);
    ebuf[pos] = make_uint2((unsigned)src[e], (unsigned)d);
  }
}

__global__ __launch_bounds__(256) void bucket_csr(const uint2* __restrict__ ebuf,
                                                  const int* __restrict__ boff,
                                                  int* __restrict__ row_ptr, int* __restrict__ col,
                                                  int N, int E) {
  __shared__ int cnt[128], exc[128], cur[128];
  const int b = blockIdx.x;
  const int node0 = b << 7;
  const int nn = min(128, N - node0);
  const int es = boff[b], ee = boff[b + 1];
  const int t = threadIdx.x;
  if (t < 128) cnt[t] = 0;
  __syncthreads();
  for (int e = es + t; e < ee; e += 256) atomicAdd(&cnt[ebuf[e].y & 127], 1);
  __syncthreads();
  if (t < 128) exc[t] = cnt[t];
  __syncthreads();
  for (int off = 1; off < 128; off <<= 1) {
    int v = 0;
    if (t < 128 && t >= off) v = exc[t - off];
    __syncthreads();
    if (t < 128) exc[t] += v;
    __syncthreads();
  }
  if (t < 128) {
    int ex = (t == 0) ? 0 : exc[t - 1];
    cur[t] = ex;
    if (t < nn) row_ptr[node0 + t] = es + ex;
  }
  __syncthreads();
  for (int e = es + t; e < ee; e += 256) {
    uint2 u = ebuf[e];
    int li = (int)(u.y & 127);
    int pos = es + atomicAdd(&cur[li], 1);
    col[pos] = (int)u.x;
  }
  if (b == 0 && t == 0) row_ptr[N] = E;
}

// ---------------- Streaming linear: y_bf16 = (optional BN affine)(x) . W ----------------
// agg(x).W == agg(x.W): W1 applied BEFORE the gather; bf16 rows halve gather lines.

template <int FIN, int FOUT, bool HAS_BN>
__global__ __launch_bounds__(256) void lin_kernel(const float* __restrict__ x,
                                                  const float* __restrict__ W,
                                                  const float* __restrict__ stats,
                                                  const float* __restrict__ gamma,
                                                  const float* __restrict__ beta, float invN,
                                                  ushort_t* __restrict__ y, int n) {
  constexpr int L = (FIN > FOUT) ? FIN : FOUT;
  constexpr int NPB = 256 / L;
  __shared__ float Ws[FIN * FOUT];
  __shared__ float xb[NPB][FIN + 1];
  const int tid = threadIdx.x;
  for (int i = tid; i < FIN * FOUT; i += 256) Ws[i] = W[i];
  const int ln = tid / L;
  const int f = tid % L;
  float scv = 1.f, ofv = 0.f;
  if (HAS_BN && f < FIN) {
    float mu = stats[f] * invN;
    float var = stats[128 + f] * invN - mu * mu;
    scv = gamma[f] * rsqrtf(var + 1e-5f);
    ofv = beta[f] - scv * mu;
  }
  __syncthreads();
  for (int base = blockIdx.x * NPB; base < n; base += gridDim.x * NPB) {
    int node = base + ln;
    bool valid = node < n;
    if (f < FIN) xb[ln][f] = valid ? fmaf(x[(size_t)node * FIN + f], scv, ofv) : 0.f;
    __syncthreads();
    if (f < FOUT && valid) {
      float acc = 0.f;
#pragma unroll 8
      for (int k = 0; k < FIN; k++) acc += xb[ln][k] * Ws[k * FOUT + f];
      y[(size_t)node * FOUT + f] = f2bf(acc);
    }
    __syncthreads();
  }
}

// ---------------- Gather (bf16 rows, fp32 accum): m = ReLU((1+eps)*y_i + sum y_j + b1) ----
// No LDS, no barrier: waves retire independently (round-6 fused version coupled
// gather+GEMM behind a block barrier and regressed 245 vs 123+45 us).

template <int F>
__global__ __launch_bounds__(256) void aggrelu_b(const ushort_t* __restrict__ y,
                                                 const int* __restrict__ row_ptr,
                                                 const int* __restrict__ col,
                                                 const float* __restrict__ epsp,
                                                 const float* __restrict__ b1,
                                                 float* __restrict__ m, int n) {
  constexpr int LPN = F / 8;      // 16B bf16x8 per lane
  constexpr int NPB = 256 / LPN;  // 32 / 64 / 128 nodes per block
  const int tid = threadIdx.x;
  const int ln = tid / LPN;
  const int fl = tid % LPN;
  const float e1 = 1.0f + epsp[0];
  const float4 b1a = ((const float4*)b1)[fl * 2];
  const float4 b1b = ((const float4*)b1)[fl * 2 + 1];

  const int node = blockIdx.x * NPB + ln;
  if (node >= n) return;
  const uint4* yr = (const uint4*)y;
  const size_t rowi = (size_t)node * LPN + fl;
  const int rs = row_ptr[node], re = row_ptr[node + 1];

  float acc[8];
#pragma unroll
  for (int j = 0; j < 8; j++) acc[j] = 0.f;

  auto addv = [&](uint4 v) {
    acc[0] += __uint_as_float(v.x << 16);
    acc[1] += __uint_as_float(v.x & 0xffff0000u);
    acc[2] += __uint_as_float(v.y << 16);
    acc[3] += __uint_as_float(v.y & 0xffff0000u);
    acc[4] += __uint_as_float(v.z << 16);
    acc[5] += __uint_as_float(v.z & 0xffff0000u);
    acc[6] += __uint_as_float(v.w << 16);
    acc[7] += __uint_as_float(v.w & 0xffff0000u);
  };

  int e = rs;
  for (; e + 4 <= re; e += 4) {
    int c0 = col[e], c1 = col[e + 1], c2 = col[e + 2], c3 = col[e + 3];
    uint4 v0 = yr[(size_t)c0 * LPN + fl];
    uint4 v1 = yr[(size_t)c1 * LPN + fl];
    uint4 v2 = yr[(size_t)c2 * LPN + fl];
    uint4 v3 = yr[(size_t)c3 * LPN + fl];
    addv(v0);
    addv(v1);
    addv(v2);
    addv(v3);
  }
  for (; e < re; e++) addv(yr[(size_t)col[e] * LPN + fl]);

  uint4 sv = yr[rowi];
  float4 r0, r1;
  r0.x = fmaxf(fmaf(e1, __uint_as_float(sv.x << 16), acc[0]) + b1a.x, 0.f);
  r0.y = fmaxf(fmaf(e1, __uint_as_float(sv.x & 0xffff0000u), acc[1]) + b1a.y, 0.f);
  r0.z = fmaxf(fmaf(e1, __uint_as_float(sv.y << 16), acc[2]) + b1a.z, 0.f);
  r0.w = fmaxf(fmaf(e1, __uint_as_float(sv.y & 0xffff0000u), acc[3]) + b1a.w, 0.f);
  r1.x = fmaxf(fmaf(e1, __uint_as_float(sv.z << 16), acc[4]) + b1b.x, 0.f);
  r1.y = fmaxf(fmaf(e1, __uint_as_float(sv.z & 0xffff0000u), acc[5]) + b1b.y, 0.f);
  r1.z = fmaxf(fmaf(e1, __uint_as_float(sv.w << 16), acc[6]) + b1b.z, 0.f);
  r1.w = fmaxf(fmaf(e1, __uint_as_float(sv.w & 0xffff0000u), acc[7]) + b1b.w, 0.f);
  float4* mo = (float4*)m;
  mo[((size_t)node * F + fl * 8) / 4] = r0;
  mo[((size_t)node * F + fl * 8) / 4 + 1] = r1;
}

// ---------------- Second linear + bias + BN-stat partials ----------------

template <int F, int NPB>
__global__ __launch_bounds__(F * NPB) void lin2s_kernel(const float* __restrict__ m,
                                                        const float* __restrict__ W,
                                                        const float* __restrict__ b,
                                                        float* __restrict__ h,
                                                        float* __restrict__ stats, int n) {
  __shared__ float Ws[F * F];
  __shared__ float bs[F];
  __shared__ float xb[NPB][F + 1];
  const int tid = threadIdx.x;
  for (int i = tid; i < F * F; i += F * NPB) Ws[i] = W[i];
  if (tid < F) bs[tid] = b[tid];
  __syncthreads();
  const int ln = tid / F;
  const int f = tid % F;
  float ssum = 0.f, ssq = 0.f;

  for (int base = blockIdx.x * NPB; base < n; base += gridDim.x * NPB) {
    int node = base + ln;
    bool valid = node < n;
    xb[ln][f] = valid ? m[(size_t)node * F + f] : 0.f;
    __syncthreads();
    float acc = bs[f];
#pragma unroll 8
    for (int k = 0; k < F; k++) acc += xb[ln][k] * Ws[k * F + f];
    if (valid) {
      h[(size_t)node * F + f] = acc;
      ssum += acc;
      ssq += acc * acc;
    }
    __syncthreads();
  }

  xb[ln][f] = ssum;
  __syncthreads();
  if (tid < F) {
    float t = 0.f;
    for (int l = 0; l < NPB; l++) t += xb[l][tid];
    atomicAdd(&stats[tid], t);
  }
  __syncthreads();
  xb[ln][f] = ssq;
  __syncthreads();
  if (tid < F) {
    float t = 0.f;
    for (int l = 0; l < NPB; l++) t += xb[l][tid];
    atomicAdd(&stats[128 + tid], t);
  }
}

// ---------------- Graph segment starts (batch is sorted) ----------------

__global__ __launch_bounds__(256) void gstart_kernel(const int* __restrict__ batch, int n,
                                                     int* __restrict__ gstart, int ng) {
  int g = blockIdx.x * blockDim.x + threadIdx.x;
  if (g > ng) return;
  int lo = 0, hi = n;
  while (lo < hi) {
    int mid = (lo + hi) >> 1;
    if (batch[mid] < g) lo = mid + 1; else hi = mid;
  }
  gstart[g] = lo;
}

// ---------------- Fused readout: BN3-affine + mean + att-c + gated pool ----------------

__global__ __launch_bounds__(256) void readout_fused(
    const float* __restrict__ h3, const int* __restrict__ gstart,
    const float* __restrict__ stats, const float* __restrict__ gamma,
    const float* __restrict__ beta, float invN, const float* __restrict__ attW,
    const float* __restrict__ attb, float* __restrict__ hg, int ng) {
  __shared__ float sM[16], oM[16], red[16][17], meanM[16], cM[16];
  const int tid = threadIdx.x;
  const int g = blockIdx.x;
  const int f = tid & 15, slot = tid >> 4;
  if (tid < 16) {
    float mu = stats[tid] * invN;
    float var = stats[128 + tid] * invN - mu * mu;
    float s = gamma[tid] * rsqrtf(var + 1e-5f);
    sM[tid] = s;
    oM[tid] = beta[tid] - s * mu;
  }
  __syncthreads();
  const int s0 = gstart[g], e0 = gstart[g + 1];
  const float sf = sM[f], of = oM[f];

  float acc = 0.f;
  for (int node = s0 + slot; node < e0; node += 16)
    acc += fmaf(h3[(size_t)node * 16 + f], sf, of);
  red[slot][f] = acc;
  __syncthreads();
  if (tid < 16) {
    float t = 0.f;
    for (int s = 0; s < 16; s++) t += red[s][tid];
    meanM[tid] = t / fmaxf((float)(e0 - s0), 1.f);
  }
  __syncthreads();
  if (tid < 16) {
    float a = attb[tid];
    for (int k = 0; k < 16; k++) a += meanM[k] * attW[k * 16 + tid];
    cM[tid] = 1.f / (1.f + expf(-a));
  }
  __syncthreads();
  const float cf = cM[f];
  float acc2 = 0.f;
  for (int node = s0 + slot; node < e0; node += 16) {
    float xv = fmaf(h3[(size_t)node * 16 + f], sf, of);
    float p = xv * cf;
    for (int m = 8; m >= 1; m >>= 1) p += __shfl_xor(p, m, 16);
    acc2 += xv / (1.f + expf(-p));
  }
  red[slot][f] = acc2;
  __syncthreads();
  if (tid < 16) {
    float t = 0.f;
    for (int s = 0; s < 16; s++) t += red[s][tid];
    hg[g * 16 + tid] = t;
  }
}

// ---------------- EFN + final: 16 lanes per graph, weights + vectors in LDS ----------------

__global__ __launch_bounds__(256) void final3_kernel(
    const float* __restrict__ hgA, const float* __restrict__ hgB, const float* __restrict__ aW1,
    const float* __restrict__ ab1, const float* __restrict__ aW2, const float* __restrict__ ab2,
    const float* __restrict__ mW, const float* __restrict__ mb, const float* __restrict__ fcW1,
    const float* __restrict__ fcb1, const float* __restrict__ fcW2,
    const float* __restrict__ fcb2, float* __restrict__ out, int ng) {
  __shared__ float aW1s[256], aW2s[256], mWs[512], fcW1s[128];
  __shared__ float ab1s[8], ab2s[32], mbs[16], fcb1s[8], fcW2s[8];
  __shared__ float fcb2s;
  __shared__ float hb[16][33], m8b[16][9], encb[16][33], abb[16][17], tb[16][9];
  const int tid = threadIdx.x;
  aW1s[tid] = aW1[tid];
  aW2s[tid] = aW2[tid];
  mWs[tid] = mW[tid];
  mWs[256 + tid] = mW[256 + tid];
  if (tid < 128) fcW1s[tid] = fcW1[tid];
  if (tid < 8) {
    ab1s[tid] = ab1[tid];
    fcb1s[tid] = fcb1[tid];
    fcW2s[tid] = fcW2[tid];
  }
  if (tid < 32) ab2s[tid] = ab2[tid];
  if (tid < 16) mbs[tid] = mb[tid];
  if (tid == 0) fcb2s = fcb2[0];
  __syncthreads();

  const int g = tid >> 4;
  const int l = tid & 15;
  const int gg = blockIdx.x * 16 + g;
  const bool valid = gg < ng;
  const float hiv = valid ? hgA[gg * 16 + l] : 0.f;
  const float hjv = valid ? hgB[gg * 16 + l] : 0.f;
  float res[3];

#pragma unroll
  for (int p = 0; p < 3; p++) {
    float ha = (p == 2) ? hjv : hiv;
    float h2 = (p == 1) ? hiv : hjv;
    hb[g][l] = ha;
    hb[g][16 + l] = h2;
    __syncthreads();
    if (l < 8) {
      float t = ab1s[l];
#pragma unroll
      for (int k = 0; k < 32; k++) t += hb[g][k] * aW1s[k * 8 + l];
      m8b[g][l] = fmaxf(t, 0.f);
    }
    __syncthreads();
    float e0 = ab2s[l], e1 = ab2s[16 + l];
#pragma unroll
    for (int k = 0; k < 8; k++) {
      float mv = m8b[g][k];
      e0 += mv * aW2s[k * 32 + l];
      e1 += mv * aW2s[k * 32 + 16 + l];
    }
    float a0 = tanhf(e0), a1 = tanhf(e1);
    encb[g][l] = fmaf(a0, ha, ha);
    encb[g][16 + l] = fmaf(a1, h2, h2);
    __syncthreads();
    float o = mbs[l];
#pragma unroll
    for (int k = 0; k < 32; k++) o += encb[g][k] * mWs[k * 16 + l];
    res[p] = fmaxf(o, 0.f);
    __syncthreads();
  }

  if (valid) {
    out[ng + gg * 16 + l] = res[0] - res[2];            // h_Ab = AB - BB
    out[ng + ng * 16 + gg * 16 + l] = res[0] - res[1];  // h_aB = AB - AA
  }
  abb[g][l] = res[0];
  __syncthreads();
  if (l < 8) {
    float t = fcb1s[l];
#pragma unroll
    for (int k = 0; k < 16; k++) t += abb[g][k] * fcW1s[k * 8 + l];
    tb[g][l] = fmaxf(t, 0.f);
  }
  __syncthreads();
  if (l == 0 && valid) {
    float sc = fcb2s;
#pragma unroll
    for (int o = 0; o < 8; o++) sc += tb[g][o] * fcW2s[o];
    out[gg] = sc;
  }
}

// ---------------- Launch ----------------

extern "C" void kernel_launch(void* const* d_in, const int* in_sizes, int n_in, void* d_out,
                              int out_size, void* d_ws, size_t ws_size, hipStream_t stream) {
  (void)n_in;
  (void)out_size;
  (void)ws_size;
  const int N = in_sizes[0] / 64;
  const int E = in_sizes[2] / 2;
  const int NG = NGRAPH;
  const int NBK = (N + 127) >> 7;
  const int CHUNK = (E + PART_BLOCKS - 1) / PART_BLOCKS;

  char* w = (char*)d_ws;
  auto alloc = [&](size_t bytes) -> void* {
    void* p = (void*)w;
    w += (bytes + 255) & ~(size_t)255;
    return p;
  };
  int* row_ptr = (int*)alloc((size_t)(N + 1) * 4);
  int* col = (int*)alloc((size_t)E * 4);
  int* hist = (int*)alloc((size_t)PART_BLOCKS * NBK * 4);
  int* totals = (int*)alloc((size_t)NBK * 4);
  int* boff = (int*)alloc((size_t)(NBK + 1) * 4);
  float* bufA = (float*)alloc((size_t)N * 64 * 4);
  float* bufB = (float*)alloc((size_t)N * 64 * 4);
  float* stats = (float*)alloc(3 * 256 * 4);
  int* gstart = (int*)alloc((size_t)(NG + 1) * 4);
  float* hgA = (float*)alloc((size_t)NG * 16 * 4);
  float* hgB = (float*)alloc((size_t)NG * 16 * 4);

  // Aliases (disjoint live ranges):
  uint2* ebuf = (uint2*)bufA;                         // CSR staging; dead before layer 1
  ushort_t* y1 = (ushort_t*)bufB;                     // bf16 N*64 = 25.6 MB
  float* m1 = bufA;                                   // fp32 N*64 = 51.2 MB
  float* h1 = bufB;                                   // fp32 N*64 (y1 dead)
  ushort_t* y2 = (ushort_t*)bufA;                     // bf16 N*32 = 12.8 MB (m1 dead)
  float* m2 = bufA + (size_t)N * 16;                  // fp32 N*32 @ +12.8 MB (disjoint y2)
  float* h2 = bufB;                                   // fp32 N*32 (h1 dead)
  ushort_t* y3 = (ushort_t*)bufA;                     // bf16 N*16 = 6.4 MB
  float* m3 = bufA + (size_t)N * 8;                   // fp32 N*16 @ +6.4 MB (disjoint y3)
  float* h3 = bufB;                                   // fp32 N*16 (h2 dead)

  const float* attW = (const float*)d_in[27];
  const float* attb = (const float*)d_in[28];
  const float invN = 1.0f / (float)N;

  for (int s = 0; s < 2; s++) {
    const float* x0 = (const float*)d_in[s];
    const int* esrc = (const int*)d_in[2 + s];
    const int* edst = esrc + E;
    const int* batch = (const int*)d_in[4 + s];
    float* hg = s ? hgB : hgA;

    // ---- bucketed CSR build (no global atomics) ----
    bucket_hist<<<PART_BLOCKS, 256, 0, stream>>>(edst, E, CHUNK, hist, NBK);
    colscan<<<(NBK + 255) / 256, 256, 0, stream>>>(hist, NBK, PART_BLOCKS, totals);
    scan_small<<<1, 1024, 0, stream>>>(totals, NBK, boff);
    partition_kernel<<<PART_BLOCKS, 256, 0, stream>>>(esrc, edst, E, CHUNK, hist, boff, ebuf,
                                                      NBK);
    bucket_csr<<<NBK, 256, 0, stream>>>(ebuf, boff, row_ptr, col, N, E);

    hipMemsetAsync(stats, 0, 3 * 256 * 4, stream);

    // ---- layer 1 ----
    lin_kernel<64, 64, false><<<2048, 256, 0, stream>>>(
        x0, (const float*)d_in[7], nullptr, nullptr, nullptr, invN, y1, N);
    aggrelu_b<64><<<(N + 31) / 32, 256, 0, stream>>>(
        y1, row_ptr, col, (const float*)d_in[6], (const float*)d_in[8], m1, N);
    lin2s_kernel<64, 4><<<2048, 256, 0, stream>>>(m1, (const float*)d_in[9],
                                                  (const float*)d_in[10], h1, stats, N);

    // ---- layer 2 ----
    lin_kernel<64, 32, true><<<2048, 256, 0, stream>>>(
        h1, (const float*)d_in[14], stats, (const float*)d_in[11], (const float*)d_in[12], invN,
        y2, N);
    aggrelu_b<32><<<(N + 63) / 64, 256, 0, stream>>>(
        y2, row_ptr, col, (const float*)d_in[13], (const float*)d_in[15], m2, N);
    lin2s_kernel<32, 8><<<2048, 256, 0, stream>>>(m2, (const float*)d_in[16],
                                                  (const float*)d_in[17], h2, stats + 256, N);

    // ---- layer 3 ----
    lin_kernel<32, 16, true><<<2048, 256, 0, stream>>>(
        h2, (const float*)d_in[21], stats + 256, (const float*)d_in[18], (const float*)d_in[19],
        invN, y3, N);
    aggrelu_b<16><<<(N + 127) / 128, 256, 0, stream>>>(
        y3, row_ptr, col, (const float*)d_in[20], (const float*)d_in[22], m3, N);
    lin2s_kernel<16, 16><<<2048, 256, 0, stream>>>(m3, (const float*)d_in[23],
                                                   (const float*)d_in[24], h3, stats + 512, N);

    // ---- fused readout (BN3 folded; batch sorted -> segment-parallel, no atomics) ----
    gstart_kernel<<<(NG + 256) / 256, 256, 0, stream>>>(batch, N, gstart, NG);
    readout_fused<<<NG, 256, 0, stream>>>(h3, gstart, stats + 512, (const float*)d_in[25],
                                          (const float*)d_in[26], invN, attW, attb, hg, NG);
  }

  final3_kernel<<<(NG + 15) / 16, 256, 0, stream>>>(
      hgA, hgB, (const float*)d_in[29], (const float*)d_in[30], (const float*)d_in[31],
      (const float*)d_in[32], (const float*)d_in[33], (const float*)d_in[34],
      (const float*)d_in[35], (const float*)d_in[36], (const float*)d_in[37],
      (const float*)d_in[38], (float*)d_out, NG);
}

// Round 8
// 1177.351 us; speedup vs baseline: 3.7534x; 1.5377x over previous
//
#include <hip/hip_runtime.h>
#include <math.h>

#define NGRAPH 1000
#define NBK_MAX 1568      // buckets of 128 nodes: ceil(200000/128)=1563
#define PART_BLOCKS 128

typedef unsigned short ushort_t;
typedef __attribute__((ext_vector_type(8))) short short8;   // 8 bf16 (4 VGPRs)
typedef __attribute__((ext_vector_type(4))) float floatx4;  // MFMA accumulator

static __device__ inline ushort_t f2bf(float f) {
  unsigned u = __float_as_uint(f);
  u = (u + 0x7fffu + ((u >> 16) & 1u)) >> 16;  // RNE
  return (ushort_t)u;
}

// ---------------- Bucketed, atomic-free CSR build ----------------

__global__ __launch_bounds__(256) void bucket_hist(const int* __restrict__ dst, int E, int chunk,
                                                   int* __restrict__ hist, int nbk) {
  __shared__ int lh[NBK_MAX];
  for (int i = threadIdx.x; i < nbk; i += 256) lh[i] = 0;
  __syncthreads();
  const int e0 = blockIdx.x * chunk;
  const int e1 = min(E, e0 + chunk);
  for (int e = e0 + threadIdx.x; e < e1; e += 256) atomicAdd(&lh[dst[e] >> 7], 1);
  __syncthreads();
  int* row = hist + (size_t)blockIdx.x * nbk;
  for (int i = threadIdx.x; i < nbk; i += 256) row[i] = lh[i];
}

__global__ __launch_bounds__(256) void colscan(int* __restrict__ hist, int nbk, int nblk,
                                               int* __restrict__ totals) {
  int b = blockIdx.x * 256 + threadIdx.x;
  if (b >= nbk) return;
  int run = 0;
  for (int k = 0; k < nblk; k++) {
    int t = hist[(size_t)k * nbk + b];
    hist[(size_t)k * nbk + b] = run;
    run += t;
  }
  totals[b] = run;
}

__global__ __launch_bounds__(1024) void scan_small(const int* __restrict__ in, int n,
                                                   int* __restrict__ out) {
  __shared__ int s[2048];
  const int t = threadIdx.x;
  s[t] = (t < n) ? in[t] : 0;
  s[t + 1024] = (t + 1024 < n) ? in[t + 1024] : 0;
  __syncthreads();
  for (int off = 1; off < 2048; off <<= 1) {
    int v0 = (t >= off) ? s[t - off] : 0;
    int v1 = ((t + 1024) >= off) ? s[t + 1024 - off] : 0;
    __syncthreads();
    s[t] += v0;
    s[t + 1024] += v1;
    __syncthreads();
  }
  if (t < n) out[t] = (t == 0) ? 0 : s[t - 1];
  const int u = t + 1024;
  if (u < n) out[u] = s[u - 1];
  if (t == 0) out[n] = s[n - 1];
}

__global__ __launch_bounds__(256) void partition_kernel(const int* __restrict__ src,
                                                        const int* __restrict__ dst, int E,
                                                        int chunk, const int* __restrict__ hist,
                                                        const int* __restrict__ boff,
                                                        uint2* __restrict__ ebuf, int nbk) {
  __shared__ int lbase[NBK_MAX];
  __shared__ int lcur[NBK_MAX];
  const int* row = hist + (size_t)blockIdx.x * nbk;
  for (int i = threadIdx.x; i < nbk; i += 256) {
    lbase[i] = boff[i] + row[i];
    lcur[i] = 0;
  }
  __syncthreads();
  const int e0 = blockIdx.x * chunk;
  const int e1 = min(E, e0 + chunk);
  for (int e = e0 + threadIdx.x; e < e1; e += 256) {
    int d = dst[e];
    int b = d >> 7;
    int pos = lbase[b] + atomicAdd(&lcur[b], 1);
    ebuf[pos] = make_uint2((unsigned)src[e], (unsigned)d);
  }
}

__global__ __launch_bounds__(256) void bucket_csr(const uint2* __restrict__ ebuf,
                                                  const int* __restrict__ boff,
                                                  int* __restrict__ row_ptr, int* __restrict__ col,
                                                  int N, int E) {
  __shared__ int cnt[128], exc[128], cur[128];
  const int b = blockIdx.x;
  const int node0 = b << 7;
  const int nn = min(128, N - node0);
  const int es = boff[b], ee = boff[b + 1];
  const int t = threadIdx.x;
  if (t < 128) cnt[t] = 0;
  __syncthreads();
  for (int e = es + t; e < ee; e += 256) atomicAdd(&cnt[ebuf[e].y & 127], 1);
  __syncthreads();
  if (t < 128) exc[t] = cnt[t];
  __syncthreads();
  for (int off = 1; off < 128; off <<= 1) {
    int v = 0;
    if (t < 128 && t >= off) v = exc[t - off];
    __syncthreads();
    if (t < 128) exc[t] += v;
    __syncthreads();
  }
  if (t < 128) {
    int ex = (t == 0) ? 0 : exc[t - 1];
    cur[t] = ex;
    if (t < nn) row_ptr[node0 + t] = es + ex;
  }
  __syncthreads();
  for (int e = es + t; e < ee; e += 256) {
    uint2 u = ebuf[e];
    int li = (int)(u.y & 127);
    int pos = es + atomicAdd(&cur[li], 1);
    col[pos] = (int)u.x;
  }
  if (b == 0 && t == 0) row_ptr[N] = E;
}

// ---------------- MFMA linear: y_bf16 = bf16(BN-affine(x_fp32)) . W1_bf16 ----------------
// Replaces the LDS-bandwidth-bound lin_kernel (2 LDS reads/FMA -> 0: B-frags in
// registers, A built on the fly). A layout: A[m=lane&15][k=quad*8+j]; D layout:
// D[row=quad*4+r][col=lane&15] (learn_hip m89/m118 verified).

template <int FIN, int FOUT, bool HAS_BN>
__global__ __launch_bounds__(256) void lin_mfma(const float* __restrict__ x,
                                                const float* __restrict__ W,
                                                const float* __restrict__ stats,
                                                const float* __restrict__ gamma,
                                                const float* __restrict__ beta, float invN,
                                                ushort_t* __restrict__ y, int n) {
  constexpr int KC = FIN / 32;   // k-chunks (FIN in {64,32})
  constexpr int FT = FOUT / 16;  // feature tiles
  __shared__ ushort_t Wbf[FIN * FOUT];
  __shared__ float scv[FIN], ofv[FIN];
  const int tid = threadIdx.x;
  for (int i = tid; i < FIN * FOUT; i += 256) Wbf[i] = f2bf(W[i]);
  for (int i = tid; i < FIN; i += 256) {
    if (HAS_BN) {
      float mu = stats[i] * invN;
      float var = stats[128 + i] * invN - mu * mu;
      float s = gamma[i] * rsqrtf(var + 1e-5f);
      scv[i] = s;
      ofv[i] = beta[i] - s * mu;
    } else {
      scv[i] = 1.f;
      ofv[i] = 0.f;
    }
  }
  __syncthreads();
  const int lane = tid & 63, wv = tid >> 6;
  const int colf = lane & 15, quad = lane >> 4, kbase = quad * 8;

  short8 Bf[FT][KC];
#pragma unroll
  for (int t = 0; t < FT; t++)
#pragma unroll
    for (int c = 0; c < KC; c++)
#pragma unroll
      for (int j = 0; j < 8; j++)
        Bf[t][c][j] = (short)Wbf[(c * 32 + kbase + j) * FOUT + t * 16 + colf];

  const floatx4 zero4 = {0.f, 0.f, 0.f, 0.f};
  const int ntiles = (n + 15) >> 4;
  for (int nt = blockIdx.x * 4 + wv; nt < ntiles; nt += gridDim.x * 4) {
    const int node0 = nt << 4;
    const int anode = node0 + colf;
    short8 Af[KC];
#pragma unroll
    for (int c = 0; c < KC; c++) {
      if (anode < n) {
        const int kk = c * 32 + kbase;
        const float* xp = x + (size_t)anode * FIN + kk;
        float4 xa = *(const float4*)xp;
        float4 xb = *(const float4*)(xp + 4);
        Af[c][0] = (short)f2bf(fmaf(xa.x, scv[kk + 0], ofv[kk + 0]));
        Af[c][1] = (short)f2bf(fmaf(xa.y, scv[kk + 1], ofv[kk + 1]));
        Af[c][2] = (short)f2bf(fmaf(xa.z, scv[kk + 2], ofv[kk + 2]));
        Af[c][3] = (short)f2bf(fmaf(xa.w, scv[kk + 3], ofv[kk + 3]));
        Af[c][4] = (short)f2bf(fmaf(xb.x, scv[kk + 4], ofv[kk + 4]));
        Af[c][5] = (short)f2bf(fmaf(xb.y, scv[kk + 5], ofv[kk + 5]));
        Af[c][6] = (short)f2bf(fmaf(xb.z, scv[kk + 6], ofv[kk + 6]));
        Af[c][7] = (short)f2bf(fmaf(xb.w, scv[kk + 7], ofv[kk + 7]));
      } else {
        Af[c] = short8{0, 0, 0, 0, 0, 0, 0, 0};
      }
    }
#pragma unroll
    for (int t = 0; t < FT; t++) {
      floatx4 acc = zero4;
#pragma unroll
      for (int c = 0; c < KC; c++)
        acc = __builtin_amdgcn_mfma_f32_16x16x32_bf16(Af[c], Bf[t][c], acc, 0, 0, 0);
#pragma unroll
      for (int r = 0; r < 4; r++) {
        const int row = node0 + quad * 4 + r;
        if (row < n) y[(size_t)row * FOUT + t * 16 + colf] = f2bf(acc[r]);
      }
    }
  }
}

// ---------------- MFMA second linear: h_fp32 = m_bf16 . W2_bf16 + b2 (+ BN stats) ----------

template <int F>
__global__ __launch_bounds__(256) void lin2s_mfma(const ushort_t* __restrict__ m,
                                                  const float* __restrict__ W,
                                                  const float* __restrict__ b,
                                                  float* __restrict__ h,
                                                  float* __restrict__ stats, int n) {
  constexpr int KC = (F + 31) / 32;  // 2,1,1
  constexpr int FT = F / 16;         // 4,2,1
  __shared__ ushort_t Wbf[F * F];
  __shared__ float bs[F], ls[F], lsq[F];
  const int tid = threadIdx.x;
  for (int i = tid; i < F * F; i += 256) Wbf[i] = f2bf(W[i]);
  if (tid < F) {
    bs[tid] = b[tid];
    ls[tid] = 0.f;
    lsq[tid] = 0.f;
  }
  __syncthreads();
  const int lane = tid & 63, wv = tid >> 6;
  const int colf = lane & 15, quad = lane >> 4, kbase = quad * 8;

  short8 Bf[FT][KC];
#pragma unroll
  for (int t = 0; t < FT; t++)
#pragma unroll
    for (int c = 0; c < KC; c++)
#pragma unroll
      for (int j = 0; j < 8; j++) {
        const int k = c * 32 + kbase + j;
        Bf[t][c][j] = (k < F) ? (short)Wbf[k * F + t * 16 + colf] : (short)0;
      }

  const floatx4 zero4 = {0.f, 0.f, 0.f, 0.f};
  float ssum[FT], ssq[FT];
#pragma unroll
  for (int t = 0; t < FT; t++) {
    ssum[t] = 0.f;
    ssq[t] = 0.f;
  }

  const int ntiles = (n + 15) >> 4;
  for (int nt = blockIdx.x * 4 + wv; nt < ntiles; nt += gridDim.x * 4) {
    const int node0 = nt << 4;
    const int anode = node0 + colf;
    short8 Af[KC];
#pragma unroll
    for (int c = 0; c < KC; c++) {
      const int kk = c * 32 + kbase;
      if (anode < n && kk < F)
        Af[c] = *(const short8*)(m + (size_t)anode * F + kk);
      else
        Af[c] = short8{0, 0, 0, 0, 0, 0, 0, 0};
    }
#pragma unroll
    for (int t = 0; t < FT; t++) {
      floatx4 acc = zero4;
#pragma unroll
      for (int c = 0; c < KC; c++)
        acc = __builtin_amdgcn_mfma_f32_16x16x32_bf16(Af[c], Bf[t][c], acc, 0, 0, 0);
      const float bv = bs[t * 16 + colf];
#pragma unroll
      for (int r = 0; r < 4; r++) {
        const int row = node0 + quad * 4 + r;
        if (row < n) {
          float o = acc[r] + bv;
          h[(size_t)row * F + t * 16 + colf] = o;
          ssum[t] += o;
          ssq[t] += o * o;
        }
      }
    }
  }
#pragma unroll
  for (int t = 0; t < FT; t++) {
    atomicAdd(&ls[t * 16 + colf], ssum[t]);
    atomicAdd(&lsq[t * 16 + colf], ssq[t]);
  }
  __syncthreads();
  if (tid < F) {
    atomicAdd(&stats[tid], ls[tid]);
    atomicAdd(&stats[128 + tid], lsq[tid]);
  }
}

// ---------------- Gather (bf16 rows, fp32 accum): m_bf16 = ReLU((1+eps)*y_i + sum y_j + b1) ----

template <int F>
__global__ __launch_bounds__(256) void aggrelu_b(const ushort_t* __restrict__ y,
                                                 const int* __restrict__ row_ptr,
                                                 const int* __restrict__ col,
                                                 const float* __restrict__ epsp,
                                                 const float* __restrict__ b1,
                                                 ushort_t* __restrict__ m, int n) {
  constexpr int LPN = F / 8;      // 16B bf16x8 per lane
  constexpr int NPB = 256 / LPN;  // 32 / 64 / 128 nodes per block
  const int tid = threadIdx.x;
  const int ln = tid / LPN;
  const int fl = tid % LPN;
  const float e1 = 1.0f + epsp[0];
  const float4 b1a = ((const float4*)b1)[fl * 2];
  const float4 b1b = ((const float4*)b1)[fl * 2 + 1];

  const int node = blockIdx.x * NPB + ln;
  if (node >= n) return;
  const uint4* yr = (const uint4*)y;
  const size_t rowi = (size_t)node * LPN + fl;
  const int rs = row_ptr[node], re = row_ptr[node + 1];

  float acc[8];
#pragma unroll
  for (int j = 0; j < 8; j++) acc[j] = 0.f;

  auto addv = [&](uint4 v) {
    acc[0] += __uint_as_float(v.x << 16);
    acc[1] += __uint_as_float(v.x & 0xffff0000u);
    acc[2] += __uint_as_float(v.y << 16);
    acc[3] += __uint_as_float(v.y & 0xffff0000u);
    acc[4] += __uint_as_float(v.z << 16);
    acc[5] += __uint_as_float(v.z & 0xffff0000u);
    acc[6] += __uint_as_float(v.w << 16);
    acc[7] += __uint_as_float(v.w & 0xffff0000u);
  };

  int e = rs;
  for (; e + 4 <= re; e += 4) {
    int c0 = col[e], c1 = col[e + 1], c2 = col[e + 2], c3 = col[e + 3];
    uint4 v0 = yr[(size_t)c0 * LPN + fl];
    uint4 v1 = yr[(size_t)c1 * LPN + fl];
    uint4 v2 = yr[(size_t)c2 * LPN + fl];
    uint4 v3 = yr[(size_t)c3 * LPN + fl];
    addv(v0);
    addv(v1);
    addv(v2);
    addv(v3);
  }
  for (; e < re; e++) addv(yr[(size_t)col[e] * LPN + fl]);

  uint4 sv = yr[rowi];
  float r0, r1, r2, r3, r4, r5, r6, r7;
  r0 = fmaxf(fmaf(e1, __uint_as_float(sv.x << 16), acc[0]) + b1a.x, 0.f);
  r1 = fmaxf(fmaf(e1, __uint_as_float(sv.x & 0xffff0000u), acc[1]) + b1a.y, 0.f);
  r2 = fmaxf(fmaf(e1, __uint_as_float(sv.y << 16), acc[2]) + b1a.z, 0.f);
  r3 = fmaxf(fmaf(e1, __uint_as_float(sv.y & 0xffff0000u), acc[3]) + b1a.w, 0.f);
  r4 = fmaxf(fmaf(e1, __uint_as_float(sv.z << 16), acc[4]) + b1b.x, 0.f);
  r5 = fmaxf(fmaf(e1, __uint_as_float(sv.z & 0xffff0000u), acc[5]) + b1b.y, 0.f);
  r6 = fmaxf(fmaf(e1, __uint_as_float(sv.w << 16), acc[6]) + b1b.z, 0.f);
  r7 = fmaxf(fmaf(e1, __uint_as_float(sv.w & 0xffff0000u), acc[7]) + b1b.w, 0.f);
  uint4 o;
  o.x = (unsigned)f2bf(r0) | ((unsigned)f2bf(r1) << 16);
  o.y = (unsigned)f2bf(r2) | ((unsigned)f2bf(r3) << 16);
  o.z = (unsigned)f2bf(r4) | ((unsigned)f2bf(r5) << 16);
  o.w = (unsigned)f2bf(r6) | ((unsigned)f2bf(r7) << 16);
  ((uint4*)m)[rowi] = o;
}

// ---------------- Graph segment starts (batch is sorted) ----------------

__global__ __launch_bounds__(256) void gstart_kernel(const int* __restrict__ batch, int n,
                                                     int* __restrict__ gstart, int ng) {
  int g = blockIdx.x * blockDim.x + threadIdx.x;
  if (g > ng) return;
  int lo = 0, hi = n;
  while (lo < hi) {
    int mid = (lo + hi) >> 1;
    if (batch[mid] < g) lo = mid + 1; else hi = mid;
  }
  gstart[g] = lo;
}

// ---------------- Fused readout: BN3-affine + mean + att-c + gated pool ----------------

__global__ __launch_bounds__(256) void readout_fused(
    const float* __restrict__ h3, const int* __restrict__ gstart,
    const float* __restrict__ stats, const float* __restrict__ gamma,
    const float* __restrict__ beta, float invN, const float* __restrict__ attW,
    const float* __restrict__ attb, float* __restrict__ hg, int ng) {
  __shared__ float sM[16], oM[16], red[16][17], meanM[16], cM[16];
  const int tid = threadIdx.x;
  const int g = blockIdx.x;
  const int f = tid & 15, slot = tid >> 4;
  if (tid < 16) {
    float mu = stats[tid] * invN;
    float var = stats[128 + tid] * invN - mu * mu;
    float s = gamma[tid] * rsqrtf(var + 1e-5f);
    sM[tid] = s;
    oM[tid] = beta[tid] - s * mu;
  }
  __syncthreads();
  const int s0 = gstart[g], e0 = gstart[g + 1];
  const float sf = sM[f], of = oM[f];

  float acc = 0.f;
  for (int node = s0 + slot; node < e0; node += 16)
    acc += fmaf(h3[(size_t)node * 16 + f], sf, of);
  red[slot][f] = acc;
  __syncthreads();
  if (tid < 16) {
    float t = 0.f;
    for (int s = 0; s < 16; s++) t += red[s][tid];
    meanM[tid] = t / fmaxf((float)(e0 - s0), 1.f);
  }
  __syncthreads();
  if (tid < 16) {
    float a = attb[tid];
    for (int k = 0; k < 16; k++) a += meanM[k] * attW[k * 16 + tid];
    cM[tid] = 1.f / (1.f + expf(-a));
  }
  __syncthreads();
  const float cf = cM[f];
  float acc2 = 0.f;
  for (int node = s0 + slot; node < e0; node += 16) {
    float xv = fmaf(h3[(size_t)node * 16 + f], sf, of);
    float p = xv * cf;
    for (int m = 8; m >= 1; m >>= 1) p += __shfl_xor(p, m, 16);
    acc2 += xv / (1.f + expf(-p));
  }
  red[slot][f] = acc2;
  __syncthreads();
  if (tid < 16) {
    float t = 0.f;
    for (int s = 0; s < 16; s++) t += red[s][tid];
    hg[g * 16 + tid] = t;
  }
}

// ---------------- EFN + final: 16 lanes per graph, weights + vectors in LDS ----------------

__global__ __launch_bounds__(256) void final3_kernel(
    const float* __restrict__ hgA, const float* __restrict__ hgB, const float* __restrict__ aW1,
    const float* __restrict__ ab1, const float* __restrict__ aW2, const float* __restrict__ ab2,
    const float* __restrict__ mW, const float* __restrict__ mb, const float* __restrict__ fcW1,
    const float* __restrict__ fcb1, const float* __restrict__ fcW2,
    const float* __restrict__ fcb2, float* __restrict__ out, int ng) {
  __shared__ float aW1s[256], aW2s[256], mWs[512], fcW1s[128];
  __shared__ float ab1s[8], ab2s[32], mbs[16], fcb1s[8], fcW2s[8];
  __shared__ float fcb2s;
  __shared__ float hb[16][33], m8b[16][9], encb[16][33], abb[16][17], tb[16][9];
  const int tid = threadIdx.x;
  aW1s[tid] = aW1[tid];
  aW2s[tid] = aW2[tid];
  mWs[tid] = mW[tid];
  mWs[256 + tid] = mW[256 + tid];
  if (tid < 128) fcW1s[tid] = fcW1[tid];
  if (tid < 8) {
    ab1s[tid] = ab1[tid];
    fcb1s[tid] = fcb1[tid];
    fcW2s[tid] = fcW2[tid];
  }
  if (tid < 32) ab2s[tid] = ab2[tid];
  if (tid < 16) mbs[tid] = mb[tid];
  if (tid == 0) fcb2s = fcb2[0];
  __syncthreads();

  const int g = tid >> 4;
  const int l = tid & 15;
  const int gg = blockIdx.x * 16 + g;
  const bool valid = gg < ng;
  const float hiv = valid ? hgA[gg * 16 + l] : 0.f;
  const float hjv = valid ? hgB[gg * 16 + l] : 0.f;
  float res[3];

#pragma unroll
  for (int p = 0; p < 3; p++) {
    float ha = (p == 2) ? hjv : hiv;
    float h2 = (p == 1) ? hiv : hjv;
    hb[g][l] = ha;
    hb[g][16 + l] = h2;
    __syncthreads();
    if (l < 8) {
      float t = ab1s[l];
#pragma unroll
      for (int k = 0; k < 32; k++) t += hb[g][k] * aW1s[k * 8 + l];
      m8b[g][l] = fmaxf(t, 0.f);
    }
    __syncthreads();
    float e0 = ab2s[l], e1 = ab2s[16 + l];
#pragma unroll
    for (int k = 0; k < 8; k++) {
      float mv = m8b[g][k];
      e0 += mv * aW2s[k * 32 + l];
      e1 += mv * aW2s[k * 32 + 16 + l];
    }
    float a0 = tanhf(e0), a1 = tanhf(e1);
    encb[g][l] = fmaf(a0, ha, ha);
    encb[g][16 + l] = fmaf(a1, h2, h2);
    __syncthreads();
    float o = mbs[l];
#pragma unroll
    for (int k = 0; k < 32; k++) o += encb[g][k] * mWs[k * 16 + l];
    res[p] = fmaxf(o, 0.f);
    __syncthreads();
  }

  if (valid) {
    out[ng + gg * 16 + l] = res[0] - res[2];            // h_Ab = AB - BB
    out[ng + ng * 16 + gg * 16 + l] = res[0] - res[1];  // h_aB = AB - AA
  }
  abb[g][l] = res[0];
  __syncthreads();
  if (l < 8) {
    float t = fcb1s[l];
#pragma unroll
    for (int k = 0; k < 16; k++) t += abb[g][k] * fcW1s[k * 8 + l];
    tb[g][l] = fmaxf(t, 0.f);
  }
  __syncthreads();
  if (l == 0 && valid) {
    float sc = fcb2s;
#pragma unroll
    for (int o = 0; o < 8; o++) sc += tb[g][o] * fcW2s[o];
    out[gg] = sc;
  }
}

// ---------------- Launch ----------------

extern "C" void kernel_launch(void* const* d_in, const int* in_sizes, int n_in, void* d_out,
                              int out_size, void* d_ws, size_t ws_size, hipStream_t stream) {
  (void)n_in;
  (void)out_size;
  (void)ws_size;
  const int N = in_sizes[0] / 64;
  const int E = in_sizes[2] / 2;
  const int NG = NGRAPH;
  const int NBK = (N + 127) >> 7;
  const int CHUNK = (E + PART_BLOCKS - 1) / PART_BLOCKS;

  char* w = (char*)d_ws;
  auto alloc = [&](size_t bytes) -> void* {
    void* p = (void*)w;
    w += (bytes + 255) & ~(size_t)255;
    return p;
  };
  int* row_ptr = (int*)alloc((size_t)(N + 1) * 4);
  int* col = (int*)alloc((size_t)E * 4);
  int* hist = (int*)alloc((size_t)PART_BLOCKS * NBK * 4);
  int* totals = (int*)alloc((size_t)NBK * 4);
  int* boff = (int*)alloc((size_t)(NBK + 1) * 4);
  float* bufA = (float*)alloc((size_t)N * 64 * 4);
  float* bufB = (float*)alloc((size_t)N * 64 * 4);
  float* stats = (float*)alloc(3 * 256 * 4);
  int* gstart = (int*)alloc((size_t)(NG + 1) * 4);
  float* hgA = (float*)alloc((size_t)NG * 16 * 4);
  float* hgB = (float*)alloc((size_t)NG * 16 * 4);

  // Aliases (disjoint live ranges), m buffers now bf16:
  uint2* ebuf = (uint2*)bufA;                          // CSR staging; dead before layer 1
  ushort_t* y1 = (ushort_t*)bufB;                      // bf16 N*64 = 25.6 MB
  ushort_t* m1 = (ushort_t*)bufA;                      // bf16 N*64 (over dead ebuf)
  float* h1 = bufB;                                    // fp32 N*64 (y1 dead)
  ushort_t* y2 = (ushort_t*)bufA;                      // bf16 N*32 = 12.8 MB (m1 dead)
  ushort_t* m2 = (ushort_t*)(bufA + (size_t)N * 16);   // bf16 N*32 @ +12.8 MB
  float* h2 = bufB;                                    // fp32 N*32 (h1 dead)
  ushort_t* y3 = (ushort_t*)bufA;                      // bf16 N*16 = 6.4 MB
  ushort_t* m3 = (ushort_t*)(bufA + (size_t)N * 8);    // bf16 N*16 @ +6.4 MB
  float* h3 = bufB;                                    // fp32 N*16 (h2 dead)

  const float* attW = (const float*)d_in[27];
  const float* attb = (const float*)d_in[28];
  const float invN = 1.0f / (float)N;

  for (int s = 0; s < 2; s++) {
    const float* x0 = (const float*)d_in[s];
    const int* esrc = (const int*)d_in[2 + s];
    const int* edst = esrc + E;
    const int* batch = (const int*)d_in[4 + s];
    float* hg = s ? hgB : hgA;

    // ---- bucketed CSR build (no global atomics) ----
    bucket_hist<<<PART_BLOCKS, 256, 0, stream>>>(edst, E, CHUNK, hist, NBK);
    colscan<<<(NBK + 255) / 256, 256, 0, stream>>>(hist, NBK, PART_BLOCKS, totals);
    scan_small<<<1, 1024, 0, stream>>>(totals, NBK, boff);
    partition_kernel<<<PART_BLOCKS, 256, 0, stream>>>(esrc, edst, E, CHUNK, hist, boff, ebuf,
                                                      NBK);
    bucket_csr<<<NBK, 256, 0, stream>>>(ebuf, boff, row_ptr, col, N, E);

    hipMemsetAsync(stats, 0, 3 * 256 * 4, stream);

    // ---- layer 1 ----
    lin_mfma<64, 64, false><<<512, 256, 0, stream>>>(
        x0, (const float*)d_in[7], nullptr, nullptr, nullptr, invN, y1, N);
    aggrelu_b<64><<<(N + 31) / 32, 256, 0, stream>>>(
        y1, row_ptr, col, (const float*)d_in[6], (const float*)d_in[8], m1, N);
    lin2s_mfma<64><<<512, 256, 0, stream>>>(m1, (const float*)d_in[9], (const float*)d_in[10],
                                            h1, stats, N);

    // ---- layer 2 ----
    lin_mfma<64, 32, true><<<512, 256, 0, stream>>>(
        h1, (const float*)d_in[14], stats, (const float*)d_in[11], (const float*)d_in[12], invN,
        y2, N);
    aggrelu_b<32><<<(N + 63) / 64, 256, 0, stream>>>(
        y2, row_ptr, col, (const float*)d_in[13], (const float*)d_in[15], m2, N);
    lin2s_mfma<32><<<512, 256, 0, stream>>>(m2, (const float*)d_in[16], (const float*)d_in[17],
                                            h2, stats + 256, N);

    // ---- layer 3 ----
    lin_mfma<32, 16, true><<<512, 256, 0, stream>>>(
        h2, (const float*)d_in[21], stats + 256, (const float*)d_in[18], (const float*)d_in[19],
        invN, y3, N);
    aggrelu_b<16><<<(N + 127) / 128, 256, 0, stream>>>(
        y3, row_ptr, col, (const float*)d_in[20], (const float*)d_in[22], m3, N);
    lin2s_mfma<16><<<512, 256, 0, stream>>>(m3, (const float*)d_in[23], (const float*)d_in[24],
                                            h3, stats + 512, N);

    // ---- fused readout (BN3 folded; batch sorted -> segment-parallel, no atomics) ----
    gstart_kernel<<<(NG + 256) / 256, 256, 0, stream>>>(batch, N, gstart, NG);
    readout_fused<<<NG, 256, 0, stream>>>(h3, gstart, stats + 512, (const float*)d_in[25],
                                          (const float*)d_in[26], invN, attW, attb, hg, NG);
  }

  final3_kernel<<<(NG + 15) / 16, 256, 0, stream>>>(
      hgA, hgB, (const float*)d_in[29], (const float*)d_in[30], (const float*)d_in[31],
      (const float*)d_in[32], (const float*)d_in[33], (const float*)d_in[34],
      (const float*)d_in[35], (const float*)d_in[36], (const float*)d_in[37],
      (const float*)d_in[38], (float*)d_out, NG);
}